// Round 8
// baseline (451.000 us; speedup 1.0000x reference)
//
#include <hip/hip_runtime.h>

// SplineCNN on MI355X — aggregate-before-GEMM, L2-direct gather (R6 structure).
//
// Math order: s[n, k*CIN+c] = deginv * sum_{m in N(n)} basis_k(n,m) * h[m,c],
// root column appended -> one dense GEMM per layer:
//   out = relu( [s | h] @ [w; root] + bias ),  K = 10*CIN, N = 64.
// Gather reads h DIRECTLY from global (L2-resident; per-XCD slice <=512KB via
// batch-aligned XCD swizzle). R7 evidence: fusing gather+GEMM starves TLP
// (occupancy 20%) -> keep split dispatches. This round: the gather's edge
// records are read as wave-uniform BROADCAST loads straight from global
// (consecutive records share a 128B line -> L1 hits; no LDS staging round
// trip), unroll 8 doubles loads-in-flight, CH=1 gather capped at 64 VGPR for
// 8 waves/SIMD. Quadrant-sorted edge lists give static accumulator targets.
// All tensors fp16 (fp32 accumulate in gather + MFMA); layer-2 GEMM epilogue
// fuses global max-pool via uint-bitcast atomicMax (relu >= 0).

#define B_   32
#define N_   512
#define F_   64
#define CAP  128          // max neighbors per node (mean ~31; P(>128) ~ 18 sigma)

typedef float f32x4 __attribute__((ext_vector_type(4)));
typedef _Float16 f16x8 __attribute__((ext_vector_type(8)));
typedef _Float16 f16x2 __attribute__((ext_vector_type(2)));

// ---------------- preprocess: quadrant-sorted edge lists ----------------
// edge record: float4 { bitcast(m), fx, fy, unused }, sorted by quad = kx0+2*ky0.
// cnt4[row] = per-quadrant counts (clamped to CAP); deginv = 1/clip(deg,1).
// Blocks 0..2047 also zero the pooled-max buffer.
__global__ __launch_bounds__(512) void preprocess_kernel(
    const float* __restrict__ adj, const float* __restrict__ coord,
    float4* __restrict__ edge, int4* __restrict__ cnt4,
    float* __restrict__ deginv, unsigned int* __restrict__ gmax) {
  int row = blockIdx.x;          // b*N + n
  int b = row >> 9;
  int tid = threadIdx.x;         // == m
  int lane = tid & 63, wave = tid >> 6;
  if (row < B_ * F_ && tid == 0) gmax[row] = 0u;
  __shared__ int wc[8][4];
  float a = adj[(size_t)row * N_ + tid];
  bool flag = (a != 0.0f);
  float cxn = coord[(size_t)row * 2 + 0];
  float cyn = coord[(size_t)row * 2 + 1];
  float cxm = coord[(size_t)(b * N_ + tid) * 2 + 0];
  float cym = coord[(size_t)(b * N_ + tid) * 2 + 1];
  float vx = (cxm - cxn + 1.0f);        // = u*2 (K-1 = 2, u in [0,1])
  float vy = (cym - cyn + 1.0f);
  float i0x = fminf(fmaxf(floorf(vx), 0.0f), 1.0f);
  float i0y = fminf(fmaxf(floorf(vy), 0.0f), 1.0f);
  float fx = vx - i0x, fy = vy - i0y;
  int quad = (int)i0x + 2 * (int)i0y;   // 0..3
  unsigned long long bq0 = __ballot(flag && quad == 0);
  unsigned long long bq1 = __ballot(flag && quad == 1);
  unsigned long long bq2 = __ballot(flag && quad == 2);
  unsigned long long bq3 = __ballot(flag && quad == 3);
  if (lane == 0) {
    wc[wave][0] = __popcll(bq0); wc[wave][1] = __popcll(bq1);
    wc[wave][2] = __popcll(bq2); wc[wave][3] = __popcll(bq3);
  }
  __syncthreads();
  int qt0 = 0, qt1 = 0, qt2 = 0, qt3 = 0;
  #pragma unroll
  for (int w2 = 0; w2 < 8; ++w2) {
    qt0 += wc[w2][0]; qt1 += wc[w2][1]; qt2 += wc[w2][2]; qt3 += wc[w2][3];
  }
  if (flag) {
    int off = 0;
    if (quad > 0) off += qt0;
    if (quad > 1) off += qt1;
    if (quad > 2) off += qt2;
    #pragma unroll
    for (int w2 = 0; w2 < 8; ++w2)
      if (w2 < wave) off += wc[w2][quad];
    unsigned long long myb = (quad == 0) ? bq0 : (quad == 1) ? bq1
                           : (quad == 2) ? bq2 : bq3;
    off += __popcll(myb & ((1ULL << lane) - 1ULL));
    if (off < CAP)
      edge[(size_t)row * CAP + off] =
          make_float4(__int_as_float(tid), fx, fy, 1.0f);
  }
  if (tid == 0) {
    int rem = CAP;
    int c0 = min(qt0, rem); rem -= c0;
    int c1 = min(qt1, rem); rem -= c1;
    int c2 = min(qt2, rem); rem -= c2;
    int c3 = min(qt3, rem);
    cnt4[row] = make_int4(c0, c1, c2, c3);
    int total = qt0 + qt1 + qt2 + qt3;
    deginv[row] = 1.0f / (float)(total > 0 ? total : 1);
  }
}

// ---- merged: x fp32->fp16 convert + pack all 3 layers' [w; root] -> Wt fp16 ----
// idx space: [0, R*32) convx (4 elems/thread); then packw for 3 layers.
__global__ void prep_misc_kernel(
    const float* __restrict__ x, _Float16* __restrict__ hx,
    const float* __restrict__ w0, const float* __restrict__ root0,
    const float* __restrict__ w1, const float* __restrict__ root1,
    const float* __restrict__ w2, const float* __restrict__ root2,
    _Float16* __restrict__ wt0, _Float16* __restrict__ wt1,
    _Float16* __restrict__ wt2) {
  int idx = blockIdx.x * blockDim.x + threadIdx.x;
  const int CX = B_ * N_ * 32;
  if (idx < CX) {
    float4 v = ((const float4*)x)[idx];
    f16x2 p0, p1;
    p0[0] = (_Float16)v.x; p0[1] = (_Float16)v.y;
    p1[0] = (_Float16)v.z; p1[1] = (_Float16)v.w;
    uint2 u;
    u.x = __builtin_bit_cast(unsigned, p0);
    u.y = __builtin_bit_cast(unsigned, p1);
    ((uint2*)hx)[idx] = u;
    return;
  }
  int r = idx - CX;
  const int S0 = 64 * 1280, S1 = 64 * 640;
  const float *w, *root; _Float16* wt; int KP, CIN;
  if (r < S0)            { w = w0; root = root0; wt = wt0; KP = 1280; CIN = 128; }
  else if (r < S0 + S1)  { w = w1; root = root1; wt = wt1; KP = 640;  CIN = 64;  r -= S0; }
  else if (r < S0 + 2*S1){ w = w2; root = root2; wt = wt2; KP = 640;  CIN = 64;  r -= S0 + S1; }
  else return;
  int f = r / KP, k = r - f * KP;
  int ks = k / CIN, c = k - ks * CIN;
  float v = (ks < 9) ? w[((size_t)ks * CIN + c) * F_ + f]
                     : root[(size_t)c * F_ + f];
  wt[(size_t)f * KP + k] = (_Float16)v;
}

// ---------------- gather: s[row, k*CIN + c] = deginv * sum basis_k * h[m,c] ----------------
// 256 threads = 4 waves, ONE ROW PER WAVE; grid 4096, XCD-swizzled so batch b's
// blocks share an XCD (h slice <=512KB L2-resident). Hot loop: wave-uniform
// BROADCAST edge-record load from global (consecutive records share a 128B
// line -> L1 hit; no LDS staging) + contiguous 128/256B h gather (L2 hit) +
// 4*CH FMAs; unroll 8 -> 8 gathers in flight. Quadrant runs give static
// accumulator targets. CH = CIN/64 channels per lane.
template<int CH, int MINW>
__global__ __launch_bounds__(256, MINW) void gather_kernel(
    const _Float16* __restrict__ hsrc,   // [16384][CIN] fp16
    const float4* __restrict__ edge, const int4* __restrict__ cnt4,
    const float* __restrict__ deginv,
    _Float16* __restrict__ sp) {         // [16384][KP]
  const int CIN = 64 * CH, KP = 10 * CIN;
  int wave = threadIdx.x >> 6, lane = threadIdx.x & 63;
  int xcd = blockIdx.x & 7;
  int j = blockIdx.x >> 3;
  int b = xcd * 4 + (j >> 7);
  int n = ((j & 127) << 2) + wave;          // row within batch
  int row = (b << 9) + n;
  int4 c4 = cnt4[row];
  int e1 = c4.x, e2 = e1 + c4.y, e3 = e2 + c4.z, e4 = e3 + c4.w;
  const float4* ep = edge + (size_t)row * CAP;
  float di = deginv[row];
  const _Float16* hb = hsrc + (size_t)b * N_ * CIN + lane * CH;

  float acc[3][3][CH];
  #pragma unroll
  for (int kx = 0; kx < 3; ++kx)
    #pragma unroll
    for (int ky = 0; ky < 3; ++ky)
      #pragma unroll
      for (int c = 0; c < CH; ++c) acc[kx][ky][c] = 0.0f;

#define EDGE_BODY(E, KX, KY) {                                        \
    float4 er = ep[E];                                                \
    int m = __float_as_int(er.x);                                     \
    float hv[CH];                                                     \
    if (CH == 1) {                                                    \
      hv[0] = (float)hb[(size_t)m * 64];                              \
    } else {                                                          \
      unsigned u = *(const unsigned*)&hb[(size_t)m * 128];            \
      f16x2 hp = __builtin_bit_cast(f16x2, u);                        \
      hv[0] = (float)hp[0]; hv[CH - 1] = (float)hp[1];                \
    }                                                                 \
    float fx = er.y, fy = er.z;                                       \
    float gx = 1.0f - fx, gy = 1.0f - fy;                             \
    float w00 = gx * gy, w01 = gx * fy, w10 = fx * gy, w11 = fx * fy; \
    _Pragma("unroll")                                                 \
    for (int c = 0; c < CH; ++c) {                                    \
      acc[KX][KY][c]         += w00 * hv[c];                          \
      acc[KX][KY + 1][c]     += w01 * hv[c];                          \
      acc[KX + 1][KY][c]     += w10 * hv[c];                          \
      acc[KX + 1][KY + 1][c] += w11 * hv[c];                          \
    } }

  #pragma unroll 8
  for (int e = 0; e < e1; ++e) EDGE_BODY(e, 0, 0)    // quad0: kx0=0, ky0=0
  #pragma unroll 8
  for (int e = e1; e < e2; ++e) EDGE_BODY(e, 1, 0)   // quad1: kx0=1, ky0=0
  #pragma unroll 8
  for (int e = e2; e < e3; ++e) EDGE_BODY(e, 0, 1)   // quad2: kx0=0, ky0=1
  #pragma unroll 8
  for (int e = e3; e < e4; ++e) EDGE_BODY(e, 1, 1)   // quad3: kx0=1, ky0=1
#undef EDGE_BODY

  // store: k = kx*3 + ky (reference reshape order); cols k*CIN + lane*CH
  _Float16* sr = sp + (size_t)row * KP + lane * CH;
  #pragma unroll
  for (int kx = 0; kx < 3; ++kx)
    #pragma unroll
    for (int ky = 0; ky < 3; ++ky) {
      int k = kx * 3 + ky;
      if (CH == 1) {
        sr[(size_t)k * CIN] = (_Float16)(acc[kx][ky][0] * di);
      } else {
        f16x2 p;
        p[0] = (_Float16)(acc[kx][ky][0] * di);
        p[1] = (_Float16)(acc[kx][ky][CH - 1] * di);
        *(f16x2*)&sr[(size_t)k * CIN] = p;
      }
    }
  // root column: h passthrough
  if (CH == 1) {
    sr[(size_t)9 * CIN] = hb[(size_t)n * 64];
  } else {
    *(unsigned*)&sr[(size_t)9 * CIN] = *(const unsigned*)&hb[(size_t)n * 128];
  }
}

// ---------------- dense GEMM: out[m,f] = relu( A[m,:]@Wt[f,:] + bias[f] ) ----------------
// A fp16 [16384][KP], Wt fp16 [64][KP]. M-tile 64 (grid 256), 256 thr = 4 waves,
// wave owns 16 rows x 64 cols, 16x16x32 f16 MFMA. Double-buffered LDS with
// issue-early/write-late staging (T14). Epilogue: fp16 h-out and/or fused
// max-pool (atomicMax on uint bits, relu >= 0).
#define GBK  64
#define GLDK 72
__global__ __launch_bounds__(256) void gemm_s_kernel(
    const _Float16* __restrict__ A, const _Float16* __restrict__ Wt,
    const float* __restrict__ bias, _Float16* __restrict__ hout,
    unsigned int* __restrict__ gmax, int KP) {
  __shared__ __attribute__((aligned(16))) _Float16 As[2][64 * GLDK];
  __shared__ __attribute__((aligned(16))) _Float16 Ws[2][64 * GLDK];
  int bm = blockIdx.x << 6;
  int tid = threadIdx.x, wave = tid >> 6, lane = tid & 63;
  int lr = lane & 15, quad = lane >> 4;
  int srow = tid >> 3, sck = (tid & 7) * 8;       // staging: rows srow, srow+32
  const size_t aoff = (size_t)(bm + srow) * KP + sck;
  const size_t woff = (size_t)srow * KP + sck;

  f32x4 acc[4] = {};
  // stage step 0 directly
  {
    *(float4*)&As[0][srow * GLDK + sck]        = *(const float4*)&A[aoff];
    *(float4*)&As[0][(srow + 32) * GLDK + sck] = *(const float4*)&A[aoff + (size_t)32 * KP];
    *(float4*)&Ws[0][srow * GLDK + sck]        = *(const float4*)&Wt[woff];
    *(float4*)&Ws[0][(srow + 32) * GLDK + sck] = *(const float4*)&Wt[woff + (size_t)32 * KP];
  }
  int S = KP / GBK, cur = 0;
  float4 pa0, pa1, pw0, pw1;
  for (int s = 0; s < S; ++s) {
    if (s + 1 < S) {                 // issue next tile's loads (no wait)
      int k0 = (s + 1) * GBK;
      pa0 = *(const float4*)&A[aoff + k0];
      pa1 = *(const float4*)&A[aoff + (size_t)32 * KP + k0];
      pw0 = *(const float4*)&Wt[woff + k0];
      pw1 = *(const float4*)&Wt[woff + (size_t)32 * KP + k0];
    }
    __syncthreads();                 // buf[cur] ready for all waves
    #pragma unroll
    for (int kk = 0; kk < GBK; kk += 32) {
      f16x8 af = *(const f16x8*)&As[cur][(16 * wave + lr) * GLDK + kk + quad * 8];
      #pragma unroll
      for (int j = 0; j < 4; ++j) {
        f16x8 bf = *(const f16x8*)&Ws[cur][(16 * j + lr) * GLDK + kk + quad * 8];
        acc[j] = __builtin_amdgcn_mfma_f32_16x16x32_f16(af, bf, acc[j], 0, 0, 0);
      }
    }
    if (s + 1 < S) {                 // write-late into the other buffer
      int nb = cur ^ 1;
      *(float4*)&As[nb][srow * GLDK + sck]        = pa0;
      *(float4*)&As[nb][(srow + 32) * GLDK + sck] = pa1;
      *(float4*)&Ws[nb][srow * GLDK + sck]        = pw0;
      *(float4*)&Ws[nb][(srow + 32) * GLDK + sck] = pw1;
    }
    cur ^= 1;
  }
  // epilogue: C layout col = lane&15, row = quad*4 + r (verified)
  int b = bm >> 9;
  #pragma unroll
  for (int j = 0; j < 4; ++j) {
    int f = 16 * j + lr;
    float bs = bias[f];
    float vmax = 0.0f;
    #pragma unroll
    for (int r = 0; r < 4; ++r) {
      int m = bm + (wave << 4) + (quad << 2) + r;
      float v = fmaxf(acc[j][r] + bs, 0.0f);
      if (hout) hout[(size_t)m * F_ + f] = (_Float16)v;
      vmax = fmaxf(vmax, v);
    }
    if (gmax) atomicMax(&gmax[(b << 6) + f], __float_as_uint(vmax));
  }
}

// ---------------- FC from pooled features ----------------
__global__ __launch_bounds__(64) void fc_kernel(
    const float* __restrict__ g, const float* __restrict__ fcw,
    const float* __restrict__ fcb, float* __restrict__ out) {
  int b = blockIdx.x;
  int f = threadIdx.x;
  __shared__ float gs[64];
  gs[f] = g[b * F_ + f];
  __syncthreads();
  if (f < 10) {
    float s = fcb[f];
    #pragma unroll
    for (int c = 0; c < 64; ++c) s += gs[c] * fcw[c * 10 + f];
    out[b * 10 + f] = s;
  }
}

extern "C" void kernel_launch(void* const* d_in, const int* in_sizes, int n_in,
                              void* d_out, int out_size, void* d_ws, size_t ws_size,
                              hipStream_t stream) {
  const float* x     = (const float*)d_in[0];
  const float* coord = (const float*)d_in[1];
  const float* adj   = (const float*)d_in[2];
  const float* w0    = (const float*)d_in[3];
  const float* root0 = (const float*)d_in[4];
  const float* b0    = (const float*)d_in[5];
  const float* w1    = (const float*)d_in[6];
  const float* root1 = (const float*)d_in[7];
  const float* b1    = (const float*)d_in[8];
  const float* w2    = (const float*)d_in[9];
  const float* root2 = (const float*)d_in[10];
  const float* b2    = (const float*)d_in[11];
  const float* fcw   = (const float*)d_in[12];
  const float* fcb   = (const float*)d_in[13];
  float* out = (float*)d_out;

  char* ws = (char*)d_ws;
  size_t off = 0;
  auto alloc = [&](size_t bytes) {
    void* p = ws + off;
    off = (off + bytes + 255) & ~(size_t)255;
    return p;
  };
  const int R = B_ * N_;  // 16384
  float4* edge    = (float4*)alloc((size_t)R * CAP * 16);
  int4*   cnt4    = (int4*)  alloc((size_t)R * 16);
  float*  deginv  = (float*) alloc((size_t)R * 4);
  _Float16* hx    = (_Float16*)alloc((size_t)R * 128 * 2);   // fp16 x
  _Float16* wt0   = (_Float16*)alloc((size_t)64 * 1280 * 2);
  _Float16* wt1   = (_Float16*)alloc((size_t)64 * 640 * 2);
  _Float16* wt2   = (_Float16*)alloc((size_t)64 * 640 * 2);
  _Float16* sp    = (_Float16*)alloc((size_t)R * 1280 * 2);  // s (max K)
  _Float16* hA    = (_Float16*)alloc((size_t)R * 64 * 2);
  _Float16* hB    = (_Float16*)alloc((size_t)R * 64 * 2);
  unsigned int* gmax = (unsigned int*)alloc((size_t)B_ * F_ * 4);

  preprocess_kernel<<<R, 512, 0, stream>>>(adj, coord, edge, cnt4, deginv, gmax);
  const int PM = R * 32 + 64 * (1280 + 640 + 640);
  prep_misc_kernel<<<(PM + 255) / 256, 256, 0, stream>>>(
      x, hx, w0, root0, w1, root1, w2, root2, wt0, wt1, wt2);

  // layer 0: CIN=128, K = 1280
  gather_kernel<2, 6><<<R / 4, 256, 0, stream>>>(hx, edge, cnt4, deginv, sp);
  gemm_s_kernel<<<R / 64, 256, 0, stream>>>(sp, wt0, b0, hA, nullptr, 1280);

  // layer 1: CIN=64, K = 640
  gather_kernel<1, 8><<<R / 4, 256, 0, stream>>>(hA, edge, cnt4, deginv, sp);
  gemm_s_kernel<<<R / 64, 256, 0, stream>>>(sp, wt1, b1, hB, nullptr, 640);

  // layer 2: CIN=64, K = 640 — fused max-pool
  gather_kernel<1, 8><<<R / 4, 256, 0, stream>>>(hB, edge, cnt4, deginv, sp);
  gemm_s_kernel<<<R / 64, 256, 0, stream>>>(sp, wt2, b2, nullptr, gmax, 640);

  fc_kernel<<<B_, 64, 0, stream>>>((const float*)gmax, fcw, fcb, out);
}

// Round 9
// 304.413 us; speedup vs baseline: 1.4815x; 1.4815x over previous
//
#include <hip/hip_runtime.h>

// SplineCNN on MI355X — aggregate-before-GEMM, L2-direct gather (R6 structure).
//
// Math order: s[n, k*CIN+c] = deginv * sum_{m in N(n)} basis_k(n,m) * h[m,c],
// root column appended -> one dense GEMM per layer:
//   out = relu( [s | h] @ [w; root] + bias ),  K = 10*CIN, N = 64.
// Gather reads h DIRECTLY from global (L2-resident; per-XCD slice <=512KB via
// batch-aligned XCD swizzle). R7: fusing gather+GEMM starves TLP -> split
// dispatches. R8 lesson: __launch_bounds__(256,8) forced VGPR=32 -> scratch
// spills (WRITE_SIZE 205MB, 112us gathers). This round: same no-LDS-staging +
// unroll-8 gather but with __launch_bounds__(256,4) (VGPR cap 128, no spills).
// Edge records are wave-uniform BROADCAST loads straight from global
// (consecutive records share 128B lines -> L1 hits; no LDS staging round trip).
// Quadrant-sorted edge lists give static accumulator targets.
// All tensors fp16 (fp32 accumulate in gather + MFMA); layer-2 GEMM epilogue
// fuses global max-pool via uint-bitcast atomicMax (relu >= 0).

#define B_   32
#define N_   512
#define F_   64
#define CAP  128          // max neighbors per node (mean ~31; P(>128) ~ 18 sigma)

typedef float f32x4 __attribute__((ext_vector_type(4)));
typedef _Float16 f16x8 __attribute__((ext_vector_type(8)));
typedef _Float16 f16x2 __attribute__((ext_vector_type(2)));

// ---------------- preprocess: quadrant-sorted edge lists ----------------
// edge record: float4 { bitcast(m), fx, fy, unused }, sorted by quad = kx0+2*ky0.
// cnt4[row] = per-quadrant counts (clamped to CAP); deginv = 1/clip(deg,1).
// Blocks 0..2047 also zero the pooled-max buffer.
__global__ __launch_bounds__(512) void preprocess_kernel(
    const float* __restrict__ adj, const float* __restrict__ coord,
    float4* __restrict__ edge, int4* __restrict__ cnt4,
    float* __restrict__ deginv, unsigned int* __restrict__ gmax) {
  int row = blockIdx.x;          // b*N + n
  int b = row >> 9;
  int tid = threadIdx.x;         // == m
  int lane = tid & 63, wave = tid >> 6;
  if (row < B_ * F_ && tid == 0) gmax[row] = 0u;
  __shared__ int wc[8][4];
  float a = adj[(size_t)row * N_ + tid];
  bool flag = (a != 0.0f);
  float cxn = coord[(size_t)row * 2 + 0];
  float cyn = coord[(size_t)row * 2 + 1];
  float cxm = coord[(size_t)(b * N_ + tid) * 2 + 0];
  float cym = coord[(size_t)(b * N_ + tid) * 2 + 1];
  float vx = (cxm - cxn + 1.0f);        // = u*2 (K-1 = 2, u in [0,1])
  float vy = (cym - cyn + 1.0f);
  float i0x = fminf(fmaxf(floorf(vx), 0.0f), 1.0f);
  float i0y = fminf(fmaxf(floorf(vy), 0.0f), 1.0f);
  float fx = vx - i0x, fy = vy - i0y;
  int quad = (int)i0x + 2 * (int)i0y;   // 0..3
  unsigned long long bq0 = __ballot(flag && quad == 0);
  unsigned long long bq1 = __ballot(flag && quad == 1);
  unsigned long long bq2 = __ballot(flag && quad == 2);
  unsigned long long bq3 = __ballot(flag && quad == 3);
  if (lane == 0) {
    wc[wave][0] = __popcll(bq0); wc[wave][1] = __popcll(bq1);
    wc[wave][2] = __popcll(bq2); wc[wave][3] = __popcll(bq3);
  }
  __syncthreads();
  int qt0 = 0, qt1 = 0, qt2 = 0, qt3 = 0;
  #pragma unroll
  for (int w2 = 0; w2 < 8; ++w2) {
    qt0 += wc[w2][0]; qt1 += wc[w2][1]; qt2 += wc[w2][2]; qt3 += wc[w2][3];
  }
  if (flag) {
    int off = 0;
    if (quad > 0) off += qt0;
    if (quad > 1) off += qt1;
    if (quad > 2) off += qt2;
    #pragma unroll
    for (int w2 = 0; w2 < 8; ++w2)
      if (w2 < wave) off += wc[w2][quad];
    unsigned long long myb = (quad == 0) ? bq0 : (quad == 1) ? bq1
                           : (quad == 2) ? bq2 : bq3;
    off += __popcll(myb & ((1ULL << lane) - 1ULL));
    if (off < CAP)
      edge[(size_t)row * CAP + off] =
          make_float4(__int_as_float(tid), fx, fy, 1.0f);
  }
  if (tid == 0) {
    int rem = CAP;
    int c0 = min(qt0, rem); rem -= c0;
    int c1 = min(qt1, rem); rem -= c1;
    int c2 = min(qt2, rem); rem -= c2;
    int c3 = min(qt3, rem);
    cnt4[row] = make_int4(c0, c1, c2, c3);
    int total = qt0 + qt1 + qt2 + qt3;
    deginv[row] = 1.0f / (float)(total > 0 ? total : 1);
  }
}

// ---- merged: x fp32->fp16 convert + pack all 3 layers' [w; root] -> Wt fp16 ----
// idx space: [0, R*32) convx (4 elems/thread); then packw for 3 layers.
__global__ void prep_misc_kernel(
    const float* __restrict__ x, _Float16* __restrict__ hx,
    const float* __restrict__ w0, const float* __restrict__ root0,
    const float* __restrict__ w1, const float* __restrict__ root1,
    const float* __restrict__ w2, const float* __restrict__ root2,
    _Float16* __restrict__ wt0, _Float16* __restrict__ wt1,
    _Float16* __restrict__ wt2) {
  int idx = blockIdx.x * blockDim.x + threadIdx.x;
  const int CX = B_ * N_ * 32;
  if (idx < CX) {
    float4 v = ((const float4*)x)[idx];
    f16x2 p0, p1;
    p0[0] = (_Float16)v.x; p0[1] = (_Float16)v.y;
    p1[0] = (_Float16)v.z; p1[1] = (_Float16)v.w;
    uint2 u;
    u.x = __builtin_bit_cast(unsigned, p0);
    u.y = __builtin_bit_cast(unsigned, p1);
    ((uint2*)hx)[idx] = u;
    return;
  }
  int r = idx - CX;
  const int S0 = 64 * 1280, S1 = 64 * 640;
  const float *w, *root; _Float16* wt; int KP, CIN;
  if (r < S0)            { w = w0; root = root0; wt = wt0; KP = 1280; CIN = 128; }
  else if (r < S0 + S1)  { w = w1; root = root1; wt = wt1; KP = 640;  CIN = 64;  r -= S0; }
  else if (r < S0 + 2*S1){ w = w2; root = root2; wt = wt2; KP = 640;  CIN = 64;  r -= S0 + S1; }
  else return;
  int f = r / KP, k = r - f * KP;
  int ks = k / CIN, c = k - ks * CIN;
  float v = (ks < 9) ? w[((size_t)ks * CIN + c) * F_ + f]
                     : root[(size_t)c * F_ + f];
  wt[(size_t)f * KP + k] = (_Float16)v;
}

// ---------------- gather: s[row, k*CIN + c] = deginv * sum basis_k * h[m,c] ----------------
// 256 threads = 4 waves, ONE ROW PER WAVE; grid 4096, XCD-swizzled so batch b's
// blocks share an XCD (h slice <=512KB L2-resident). Hot loop: wave-uniform
// BROADCAST edge-record load from global (consecutive records share a 128B
// line -> L1 hit; no LDS staging) + contiguous 128/256B h gather (L2 hit) +
// 4*CH FMAs; unroll 8 -> 8 gathers in flight. launch_bounds(256,4): VGPR cap
// 128 so the unrolled pipeline fits WITHOUT scratch spills (R8: cap 64 ->
// VGPR 32 -> 205MB spill traffic, 3x regression). Quadrant runs give static
// accumulator targets. CH = CIN/64 channels per lane.
template<int CH>
__global__ __launch_bounds__(256, 4) void gather_kernel(
    const _Float16* __restrict__ hsrc,   // [16384][CIN] fp16
    const float4* __restrict__ edge, const int4* __restrict__ cnt4,
    const float* __restrict__ deginv,
    _Float16* __restrict__ sp) {         // [16384][KP]
  const int CIN = 64 * CH, KP = 10 * CIN;
  int wave = threadIdx.x >> 6, lane = threadIdx.x & 63;
  int xcd = blockIdx.x & 7;
  int j = blockIdx.x >> 3;
  int b = xcd * 4 + (j >> 7);
  int n = ((j & 127) << 2) + wave;          // row within batch
  int row = (b << 9) + n;
  int4 c4 = cnt4[row];
  int e1 = c4.x, e2 = e1 + c4.y, e3 = e2 + c4.z, e4 = e3 + c4.w;
  const float4* ep = edge + (size_t)row * CAP;
  float di = deginv[row];
  const _Float16* hb = hsrc + (size_t)b * N_ * CIN + lane * CH;

  float acc[3][3][CH];
  #pragma unroll
  for (int kx = 0; kx < 3; ++kx)
    #pragma unroll
    for (int ky = 0; ky < 3; ++ky)
      #pragma unroll
      for (int c = 0; c < CH; ++c) acc[kx][ky][c] = 0.0f;

#define EDGE_BODY(E, KX, KY) {                                        \
    float4 er = ep[E];                                                \
    int m = __float_as_int(er.x);                                     \
    float hv[CH];                                                     \
    if (CH == 1) {                                                    \
      hv[0] = (float)hb[(size_t)m * 64];                              \
    } else {                                                          \
      unsigned u = *(const unsigned*)&hb[(size_t)m * 128];            \
      f16x2 hp = __builtin_bit_cast(f16x2, u);                        \
      hv[0] = (float)hp[0]; hv[CH - 1] = (float)hp[1];                \
    }                                                                 \
    float fx = er.y, fy = er.z;                                       \
    float gx = 1.0f - fx, gy = 1.0f - fy;                             \
    float w00 = gx * gy, w01 = gx * fy, w10 = fx * gy, w11 = fx * fy; \
    _Pragma("unroll")                                                 \
    for (int c = 0; c < CH; ++c) {                                    \
      acc[KX][KY][c]         += w00 * hv[c];                          \
      acc[KX][KY + 1][c]     += w01 * hv[c];                          \
      acc[KX + 1][KY][c]     += w10 * hv[c];                          \
      acc[KX + 1][KY + 1][c] += w11 * hv[c];                          \
    } }

  #pragma unroll 8
  for (int e = 0; e < e1; ++e) EDGE_BODY(e, 0, 0)    // quad0: kx0=0, ky0=0
  #pragma unroll 8
  for (int e = e1; e < e2; ++e) EDGE_BODY(e, 1, 0)   // quad1: kx0=1, ky0=0
  #pragma unroll 8
  for (int e = e2; e < e3; ++e) EDGE_BODY(e, 0, 1)   // quad2: kx0=0, ky0=1
  #pragma unroll 8
  for (int e = e3; e < e4; ++e) EDGE_BODY(e, 1, 1)   // quad3: kx0=1, ky0=1
#undef EDGE_BODY

  // store: k = kx*3 + ky (reference reshape order); cols k*CIN + lane*CH
  _Float16* sr = sp + (size_t)row * KP + lane * CH;
  #pragma unroll
  for (int kx = 0; kx < 3; ++kx)
    #pragma unroll
    for (int ky = 0; ky < 3; ++ky) {
      int k = kx * 3 + ky;
      if (CH == 1) {
        sr[(size_t)k * CIN] = (_Float16)(acc[kx][ky][0] * di);
      } else {
        f16x2 p;
        p[0] = (_Float16)(acc[kx][ky][0] * di);
        p[1] = (_Float16)(acc[kx][ky][CH - 1] * di);
        *(f16x2*)&sr[(size_t)k * CIN] = p;
      }
    }
  // root column: h passthrough
  if (CH == 1) {
    sr[(size_t)9 * CIN] = hb[(size_t)n * 64];
  } else {
    *(unsigned*)&sr[(size_t)9 * CIN] = *(const unsigned*)&hb[(size_t)n * 128];
  }
}

// ---------------- dense GEMM: out[m,f] = relu( A[m,:]@Wt[f,:] + bias[f] ) ----------------
// A fp16 [16384][KP], Wt fp16 [64][KP]. M-tile 64 (grid 256), 256 thr = 4 waves,
// wave owns 16 rows x 64 cols, 16x16x32 f16 MFMA. Double-buffered LDS with
// issue-early/write-late staging (T14). Epilogue: fp16 h-out and/or fused
// max-pool (atomicMax on uint bits, relu >= 0).
#define GBK  64
#define GLDK 72
__global__ __launch_bounds__(256) void gemm_s_kernel(
    const _Float16* __restrict__ A, const _Float16* __restrict__ Wt,
    const float* __restrict__ bias, _Float16* __restrict__ hout,
    unsigned int* __restrict__ gmax, int KP) {
  __shared__ __attribute__((aligned(16))) _Float16 As[2][64 * GLDK];
  __shared__ __attribute__((aligned(16))) _Float16 Ws[2][64 * GLDK];
  int bm = blockIdx.x << 6;
  int tid = threadIdx.x, wave = tid >> 6, lane = tid & 63;
  int lr = lane & 15, quad = lane >> 4;
  int srow = tid >> 3, sck = (tid & 7) * 8;       // staging: rows srow, srow+32
  const size_t aoff = (size_t)(bm + srow) * KP + sck;
  const size_t woff = (size_t)srow * KP + sck;

  f32x4 acc[4] = {};
  // stage step 0 directly
  {
    *(float4*)&As[0][srow * GLDK + sck]        = *(const float4*)&A[aoff];
    *(float4*)&As[0][(srow + 32) * GLDK + sck] = *(const float4*)&A[aoff + (size_t)32 * KP];
    *(float4*)&Ws[0][srow * GLDK + sck]        = *(const float4*)&Wt[woff];
    *(float4*)&Ws[0][(srow + 32) * GLDK + sck] = *(const float4*)&Wt[woff + (size_t)32 * KP];
  }
  int S = KP / GBK, cur = 0;
  float4 pa0, pa1, pw0, pw1;
  for (int s = 0; s < S; ++s) {
    if (s + 1 < S) {                 // issue next tile's loads (no wait)
      int k0 = (s + 1) * GBK;
      pa0 = *(const float4*)&A[aoff + k0];
      pa1 = *(const float4*)&A[aoff + (size_t)32 * KP + k0];
      pw0 = *(const float4*)&Wt[woff + k0];
      pw1 = *(const float4*)&Wt[woff + (size_t)32 * KP + k0];
    }
    __syncthreads();                 // buf[cur] ready for all waves
    #pragma unroll
    for (int kk = 0; kk < GBK; kk += 32) {
      f16x8 af = *(const f16x8*)&As[cur][(16 * wave + lr) * GLDK + kk + quad * 8];
      #pragma unroll
      for (int j = 0; j < 4; ++j) {
        f16x8 bf = *(const f16x8*)&Ws[cur][(16 * j + lr) * GLDK + kk + quad * 8];
        acc[j] = __builtin_amdgcn_mfma_f32_16x16x32_f16(af, bf, acc[j], 0, 0, 0);
      }
    }
    if (s + 1 < S) {                 // write-late into the other buffer
      int nb = cur ^ 1;
      *(float4*)&As[nb][srow * GLDK + sck]        = pa0;
      *(float4*)&As[nb][(srow + 32) * GLDK + sck] = pa1;
      *(float4*)&Ws[nb][srow * GLDK + sck]        = pw0;
      *(float4*)&Ws[nb][(srow + 32) * GLDK + sck] = pw1;
    }
    cur ^= 1;
  }
  // epilogue: C layout col = lane&15, row = quad*4 + r (verified)
  int b = bm >> 9;
  #pragma unroll
  for (int j = 0; j < 4; ++j) {
    int f = 16 * j + lr;
    float bs = bias[f];
    float vmax = 0.0f;
    #pragma unroll
    for (int r = 0; r < 4; ++r) {
      int m = bm + (wave << 4) + (quad << 2) + r;
      float v = fmaxf(acc[j][r] + bs, 0.0f);
      if (hout) hout[(size_t)m * F_ + f] = (_Float16)v;
      vmax = fmaxf(vmax, v);
    }
    if (gmax) atomicMax(&gmax[(b << 6) + f], __float_as_uint(vmax));
  }
}

// ---------------- FC from pooled features ----------------
__global__ __launch_bounds__(64) void fc_kernel(
    const float* __restrict__ g, const float* __restrict__ fcw,
    const float* __restrict__ fcb, float* __restrict__ out) {
  int b = blockIdx.x;
  int f = threadIdx.x;
  __shared__ float gs[64];
  gs[f] = g[b * F_ + f];
  __syncthreads();
  if (f < 10) {
    float s = fcb[f];
    #pragma unroll
    for (int c = 0; c < 64; ++c) s += gs[c] * fcw[c * 10 + f];
    out[b * 10 + f] = s;
  }
}

extern "C" void kernel_launch(void* const* d_in, const int* in_sizes, int n_in,
                              void* d_out, int out_size, void* d_ws, size_t ws_size,
                              hipStream_t stream) {
  const float* x     = (const float*)d_in[0];
  const float* coord = (const float*)d_in[1];
  const float* adj   = (const float*)d_in[2];
  const float* w0    = (const float*)d_in[3];
  const float* root0 = (const float*)d_in[4];
  const float* b0    = (const float*)d_in[5];
  const float* w1    = (const float*)d_in[6];
  const float* root1 = (const float*)d_in[7];
  const float* b1    = (const float*)d_in[8];
  const float* w2    = (const float*)d_in[9];
  const float* root2 = (const float*)d_in[10];
  const float* b2    = (const float*)d_in[11];
  const float* fcw   = (const float*)d_in[12];
  const float* fcb   = (const float*)d_in[13];
  float* out = (float*)d_out;

  char* ws = (char*)d_ws;
  size_t off = 0;
  auto alloc = [&](size_t bytes) {
    void* p = ws + off;
    off = (off + bytes + 255) & ~(size_t)255;
    return p;
  };
  const int R = B_ * N_;  // 16384
  float4* edge    = (float4*)alloc((size_t)R * CAP * 16);
  int4*   cnt4    = (int4*)  alloc((size_t)R * 16);
  float*  deginv  = (float*) alloc((size_t)R * 4);
  _Float16* hx    = (_Float16*)alloc((size_t)R * 128 * 2);   // fp16 x
  _Float16* wt0   = (_Float16*)alloc((size_t)64 * 1280 * 2);
  _Float16* wt1   = (_Float16*)alloc((size_t)64 * 640 * 2);
  _Float16* wt2   = (_Float16*)alloc((size_t)64 * 640 * 2);
  _Float16* sp    = (_Float16*)alloc((size_t)R * 1280 * 2);  // s (max K)
  _Float16* hA    = (_Float16*)alloc((size_t)R * 64 * 2);
  _Float16* hB    = (_Float16*)alloc((size_t)R * 64 * 2);
  unsigned int* gmax = (unsigned int*)alloc((size_t)B_ * F_ * 4);

  preprocess_kernel<<<R, 512, 0, stream>>>(adj, coord, edge, cnt4, deginv, gmax);
  const int PM = R * 32 + 64 * (1280 + 640 + 640);
  prep_misc_kernel<<<(PM + 255) / 256, 256, 0, stream>>>(
      x, hx, w0, root0, w1, root1, w2, root2, wt0, wt1, wt2);

  // layer 0: CIN=128, K = 1280
  gather_kernel<2><<<R / 4, 256, 0, stream>>>(hx, edge, cnt4, deginv, sp);
  gemm_s_kernel<<<R / 64, 256, 0, stream>>>(sp, wt0, b0, hA, nullptr, 1280);

  // layer 1: CIN=64, K = 640
  gather_kernel<1><<<R / 4, 256, 0, stream>>>(hA, edge, cnt4, deginv, sp);
  gemm_s_kernel<<<R / 64, 256, 0, stream>>>(sp, wt1, b1, hB, nullptr, 640);

  // layer 2: CIN=64, K = 640 — fused max-pool
  gather_kernel<1><<<R / 4, 256, 0, stream>>>(hB, edge, cnt4, deginv, sp);
  gemm_s_kernel<<<R / 64, 256, 0, stream>>>(sp, wt2, b2, nullptr, gmax, 640);

  fc_kernel<<<B_, 64, 0, stream>>>((const float*)gmax, fcw, fcb, out);
}

// Round 10
// 274.235 us; speedup vs baseline: 1.6446x; 1.1100x over previous
//
#include <hip/hip_runtime.h>

// SplineCNN on MI355X — aggregate-before-GEMM; row-per-block, quadrant-per-wave gather.
//
// Math order: s[n, k*CIN+c] = deginv * sum_{m in N(n)} basis_k(n,m) * h[m,c],
// root column appended -> one dense GEMM per layer:
//   out = relu( [s | h] @ [w; root] + bias ),  K = 10*CIN, N = 64.
// Gather evidence trail: R6 L2-direct+per-wave-staging = 52us/layer; R8/R9
// broadcast-loads-from-global = worse (serialized VMEM in dynamic loop; R8's
// launch_bounds(256,8) additionally spilled). Per-edge dependent chain with
// one row per wave is the latency wall. THIS ROUND: one row per BLOCK —
// 4 waves each take one quadrant run (chain /4, static 2x2 accumulator = 4-8
// VGPR), edge list staged once by a single coalesced 128-thread load into
// LDS, partials reduced via a static quad/slot->k mapping in LDS, fp16 store.
// Grid 16384 blocks, tiny VGPR/LDS -> high occupancy + tail balance.
// All tensors fp16 (fp32 accumulate in gather + MFMA); layer-2 GEMM epilogue
// fuses global max-pool via uint-bitcast atomicMax (relu >= 0).

#define B_   32
#define N_   512
#define F_   64
#define CAP  128          // max neighbors per node (mean ~31; P(>128) ~ 18 sigma)

typedef float f32x4 __attribute__((ext_vector_type(4)));
typedef _Float16 f16x8 __attribute__((ext_vector_type(8)));
typedef _Float16 f16x2 __attribute__((ext_vector_type(2)));

// ---------------- preprocess: quadrant-sorted edge lists ----------------
// edge record: float4 { bitcast(m), fx, fy, unused }, sorted by quad = kx0+2*ky0.
// cnt4[row] = per-quadrant counts (clamped to CAP); deginv = 1/clip(deg,1).
// Blocks 0..2047 also zero the pooled-max buffer.
__global__ __launch_bounds__(512) void preprocess_kernel(
    const float* __restrict__ adj, const float* __restrict__ coord,
    float4* __restrict__ edge, int4* __restrict__ cnt4,
    float* __restrict__ deginv, unsigned int* __restrict__ gmax) {
  int row = blockIdx.x;          // b*N + n
  int b = row >> 9;
  int tid = threadIdx.x;         // == m
  int lane = tid & 63, wave = tid >> 6;
  if (row < B_ * F_ && tid == 0) gmax[row] = 0u;
  __shared__ int wc[8][4];
  float a = adj[(size_t)row * N_ + tid];
  bool flag = (a != 0.0f);
  float cxn = coord[(size_t)row * 2 + 0];
  float cyn = coord[(size_t)row * 2 + 1];
  float cxm = coord[(size_t)(b * N_ + tid) * 2 + 0];
  float cym = coord[(size_t)(b * N_ + tid) * 2 + 1];
  float vx = (cxm - cxn + 1.0f);        // = u*2 (K-1 = 2, u in [0,1])
  float vy = (cym - cyn + 1.0f);
  float i0x = fminf(fmaxf(floorf(vx), 0.0f), 1.0f);
  float i0y = fminf(fmaxf(floorf(vy), 0.0f), 1.0f);
  float fx = vx - i0x, fy = vy - i0y;
  int quad = (int)i0x + 2 * (int)i0y;   // 0..3
  unsigned long long bq0 = __ballot(flag && quad == 0);
  unsigned long long bq1 = __ballot(flag && quad == 1);
  unsigned long long bq2 = __ballot(flag && quad == 2);
  unsigned long long bq3 = __ballot(flag && quad == 3);
  if (lane == 0) {
    wc[wave][0] = __popcll(bq0); wc[wave][1] = __popcll(bq1);
    wc[wave][2] = __popcll(bq2); wc[wave][3] = __popcll(bq3);
  }
  __syncthreads();
  int qt0 = 0, qt1 = 0, qt2 = 0, qt3 = 0;
  #pragma unroll
  for (int w2 = 0; w2 < 8; ++w2) {
    qt0 += wc[w2][0]; qt1 += wc[w2][1]; qt2 += wc[w2][2]; qt3 += wc[w2][3];
  }
  if (flag) {
    int off = 0;
    if (quad > 0) off += qt0;
    if (quad > 1) off += qt1;
    if (quad > 2) off += qt2;
    #pragma unroll
    for (int w2 = 0; w2 < 8; ++w2)
      if (w2 < wave) off += wc[w2][quad];
    unsigned long long myb = (quad == 0) ? bq0 : (quad == 1) ? bq1
                           : (quad == 2) ? bq2 : bq3;
    off += __popcll(myb & ((1ULL << lane) - 1ULL));
    if (off < CAP)
      edge[(size_t)row * CAP + off] =
          make_float4(__int_as_float(tid), fx, fy, 1.0f);
  }
  if (tid == 0) {
    int rem = CAP;
    int c0 = min(qt0, rem); rem -= c0;
    int c1 = min(qt1, rem); rem -= c1;
    int c2 = min(qt2, rem); rem -= c2;
    int c3 = min(qt3, rem);
    cnt4[row] = make_int4(c0, c1, c2, c3);
    int total = qt0 + qt1 + qt2 + qt3;
    deginv[row] = 1.0f / (float)(total > 0 ? total : 1);
  }
}

// ---- merged: x fp32->fp16 convert + pack all 3 layers' [w; root] -> Wt fp16 ----
__global__ void prep_misc_kernel(
    const float* __restrict__ x, _Float16* __restrict__ hx,
    const float* __restrict__ w0, const float* __restrict__ root0,
    const float* __restrict__ w1, const float* __restrict__ root1,
    const float* __restrict__ w2, const float* __restrict__ root2,
    _Float16* __restrict__ wt0, _Float16* __restrict__ wt1,
    _Float16* __restrict__ wt2) {
  int idx = blockIdx.x * blockDim.x + threadIdx.x;
  const int CX = B_ * N_ * 32;
  if (idx < CX) {
    float4 v = ((const float4*)x)[idx];
    f16x2 p0, p1;
    p0[0] = (_Float16)v.x; p0[1] = (_Float16)v.y;
    p1[0] = (_Float16)v.z; p1[1] = (_Float16)v.w;
    uint2 u;
    u.x = __builtin_bit_cast(unsigned, p0);
    u.y = __builtin_bit_cast(unsigned, p1);
    ((uint2*)hx)[idx] = u;
    return;
  }
  int r = idx - CX;
  const int S0 = 64 * 1280, S1 = 64 * 640;
  const float *w, *root; _Float16* wt; int KP, CIN;
  if (r < S0)            { w = w0; root = root0; wt = wt0; KP = 1280; CIN = 128; }
  else if (r < S0 + S1)  { w = w1; root = root1; wt = wt1; KP = 640;  CIN = 64;  r -= S0; }
  else if (r < S0 + 2*S1){ w = w2; root = root2; wt = wt2; KP = 640;  CIN = 64;  r -= S0 + S1; }
  else return;
  int f = r / KP, k = r - f * KP;
  int ks = k / CIN, c = k - ks * CIN;
  float v = (ks < 9) ? w[((size_t)ks * CIN + c) * F_ + f]
                     : root[(size_t)c * F_ + f];
  wt[(size_t)f * KP + k] = (_Float16)v;
}

// ---------------- gather: one row per BLOCK, one quadrant per WAVE ----------------
// 256 threads = 4 waves; grid 16384 (XCD-swizzled: batch b on XCD b>>2, h slice
// L2-resident). Stage: one coalesced 128-thread load of the row's edge list
// into LDS. Wave w processes quadrant-w's run with a STATIC 2x2xCH accumulator
// (quad is wave-uniform). Partials -> LDS; 256-thread reduction combines quads
// into the 9 k-slots via the static map k=(qx+rkx)*3+(qy+rky), *deginv, fp16
// store (+root passthrough). Tiny VGPR/LDS -> high occupancy; chain length /4.
template<int CH>
__global__ __launch_bounds__(256) void gather_kernel(
    const _Float16* __restrict__ hsrc,   // [16384][CIN] fp16
    const float4* __restrict__ edge, const int4* __restrict__ cnt4,
    const float* __restrict__ deginv,
    _Float16* __restrict__ sp) {         // [16384][KP]
  const int CIN = 64 * CH, KP = 10 * CIN;
  __shared__ float4 esh[CAP];
  __shared__ float part[4][4][64 * CH];  // [wave(quad)][slot rkx*2+rky][ch]
  int tid = threadIdx.x, wave = tid >> 6, lane = tid & 63;
  int xcd = blockIdx.x & 7, j = blockIdx.x >> 3;   // j in 0..2047
  int b = xcd * 4 + (j >> 9);
  int n = j & 511;
  int row = (b << 9) + n;
  int4 c4 = cnt4[row];
  int e1 = c4.x, e2 = e1 + c4.y, e3 = e2 + c4.z, e4 = e3 + c4.w;
  if (tid < e4) esh[tid] = edge[(size_t)row * CAP + tid];
  __syncthreads();

  int qs = (wave == 0) ? 0 : (wave == 1) ? e1 : (wave == 2) ? e2 : e3;
  int qe = (wave == 0) ? e1 : (wave == 1) ? e2 : (wave == 2) ? e3 : e4;
  const _Float16* hb = hsrc + (size_t)b * N_ * CIN + lane * CH;

  float a00[CH] = {}, a01[CH] = {}, a10[CH] = {}, a11[CH] = {};
  #pragma unroll 4
  for (int e = qs; e < qe; ++e) {
    float4 er = esh[e];
    int m = __float_as_int(er.x);
    float hv[CH];
    if (CH == 1) {
      hv[0] = (float)hb[(size_t)m * 64];
    } else {
      unsigned u = *(const unsigned*)&hb[(size_t)m * 128];
      f16x2 hp = __builtin_bit_cast(f16x2, u);
      hv[0] = (float)hp[0]; hv[CH - 1] = (float)hp[1];
    }
    float fx = er.y, fy = er.z;
    float gx = 1.0f - fx, gy = 1.0f - fy;
    #pragma unroll
    for (int c = 0; c < CH; ++c) {
      a00[c] += (gx * gy) * hv[c];   // (rkx,rky) = (0,0)
      a01[c] += (gx * fy) * hv[c];   // (0,1)
      a10[c] += (fx * gy) * hv[c];   // (1,0)
      a11[c] += (fx * fy) * hv[c];   // (1,1)
    }
  }
  #pragma unroll
  for (int c = 0; c < CH; ++c) {
    part[wave][0][lane * CH + c] = a00[c];
    part[wave][1][lane * CH + c] = a01[c];
    part[wave][2][lane * CH + c] = a10[c];
    part[wave][3][lane * CH + c] = a11[c];
  }
  __syncthreads();

  // reduction: thread t covers k = (t>>6), +4, +8; channel pair (t&63)*CH
  float di = deginv[row];
  _Float16* sr = sp + (size_t)row * KP + lane * CH;
  for (int k = wave; k < 9; k += 4) {
    int kx = k / 3, ky = k - 3 * kx;
    float v[CH] = {};
    #pragma unroll
    for (int qx = 0; qx < 2; ++qx)
      #pragma unroll
      for (int qy = 0; qy < 2; ++qy) {
        int rkx = kx - qx, rky = ky - qy;
        if (rkx >= 0 && rkx <= 1 && rky >= 0 && rky <= 1) {
          int w = qy * 2 + qx, s = rkx * 2 + rky;
          #pragma unroll
          for (int c = 0; c < CH; ++c) v[c] += part[w][s][lane * CH + c];
        }
      }
    if (CH == 1) {
      sr[(size_t)k * CIN] = (_Float16)(v[0] * di);
    } else {
      f16x2 p;
      p[0] = (_Float16)(v[0] * di);
      p[1] = (_Float16)(v[CH - 1] * di);
      *(f16x2*)&sr[(size_t)k * CIN] = p;
    }
  }
  // root column: h passthrough (first wave only)
  if (wave == 0) {
    if (CH == 1) {
      sr[(size_t)9 * CIN] = hb[(size_t)n * 64];
    } else {
      *(unsigned*)&sr[(size_t)9 * CIN] = *(const unsigned*)&hb[(size_t)n * 128];
    }
  }
}

// ---------------- dense GEMM: out[m,f] = relu( A[m,:]@Wt[f,:] + bias[f] ) ----------------
// A fp16 [16384][KP], Wt fp16 [64][KP]. M-tile 64 (grid 256), 256 thr = 4 waves,
// wave owns 16 rows x 64 cols, 16x16x32 f16 MFMA. Double-buffered LDS with
// issue-early/write-late staging (T14). Epilogue: fp16 h-out and/or fused
// max-pool (atomicMax on uint bits, relu >= 0).
#define GBK  64
#define GLDK 72
__global__ __launch_bounds__(256) void gemm_s_kernel(
    const _Float16* __restrict__ A, const _Float16* __restrict__ Wt,
    const float* __restrict__ bias, _Float16* __restrict__ hout,
    unsigned int* __restrict__ gmax, int KP) {
  __shared__ __attribute__((aligned(16))) _Float16 As[2][64 * GLDK];
  __shared__ __attribute__((aligned(16))) _Float16 Ws[2][64 * GLDK];
  int bm = blockIdx.x << 6;
  int tid = threadIdx.x, wave = tid >> 6, lane = tid & 63;
  int lr = lane & 15, quad = lane >> 4;
  int srow = tid >> 3, sck = (tid & 7) * 8;       // staging: rows srow, srow+32
  const size_t aoff = (size_t)(bm + srow) * KP + sck;
  const size_t woff = (size_t)srow * KP + sck;

  f32x4 acc[4] = {};
  // stage step 0 directly
  {
    *(float4*)&As[0][srow * GLDK + sck]        = *(const float4*)&A[aoff];
    *(float4*)&As[0][(srow + 32) * GLDK + sck] = *(const float4*)&A[aoff + (size_t)32 * KP];
    *(float4*)&Ws[0][srow * GLDK + sck]        = *(const float4*)&Wt[woff];
    *(float4*)&Ws[0][(srow + 32) * GLDK + sck] = *(const float4*)&Wt[woff + (size_t)32 * KP];
  }
  int S = KP / GBK, cur = 0;
  float4 pa0, pa1, pw0, pw1;
  for (int s = 0; s < S; ++s) {
    if (s + 1 < S) {                 // issue next tile's loads (no wait)
      int k0 = (s + 1) * GBK;
      pa0 = *(const float4*)&A[aoff + k0];
      pa1 = *(const float4*)&A[aoff + (size_t)32 * KP + k0];
      pw0 = *(const float4*)&Wt[woff + k0];
      pw1 = *(const float4*)&Wt[woff + (size_t)32 * KP + k0];
    }
    __syncthreads();                 // buf[cur] ready for all waves
    #pragma unroll
    for (int kk = 0; kk < GBK; kk += 32) {
      f16x8 af = *(const f16x8*)&As[cur][(16 * wave + lr) * GLDK + kk + quad * 8];
      #pragma unroll
      for (int j = 0; j < 4; ++j) {
        f16x8 bf = *(const f16x8*)&Ws[cur][(16 * j + lr) * GLDK + kk + quad * 8];
        acc[j] = __builtin_amdgcn_mfma_f32_16x16x32_f16(af, bf, acc[j], 0, 0, 0);
      }
    }
    if (s + 1 < S) {                 // write-late into the other buffer
      int nb = cur ^ 1;
      *(float4*)&As[nb][srow * GLDK + sck]        = pa0;
      *(float4*)&As[nb][(srow + 32) * GLDK + sck] = pa1;
      *(float4*)&Ws[nb][srow * GLDK + sck]        = pw0;
      *(float4*)&Ws[nb][(srow + 32) * GLDK + sck] = pw1;
    }
    cur ^= 1;
  }
  // epilogue: C layout col = lane&15, row = quad*4 + r (verified)
  int b = bm >> 9;
  #pragma unroll
  for (int j = 0; j < 4; ++j) {
    int f = 16 * j + lr;
    float bs = bias[f];
    float vmax = 0.0f;
    #pragma unroll
    for (int r = 0; r < 4; ++r) {
      int m = bm + (wave << 4) + (quad << 2) + r;
      float v = fmaxf(acc[j][r] + bs, 0.0f);
      if (hout) hout[(size_t)m * F_ + f] = (_Float16)v;
      vmax = fmaxf(vmax, v);
    }
    if (gmax) atomicMax(&gmax[(b << 6) + f], __float_as_uint(vmax));
  }
}

// ---------------- FC from pooled features ----------------
__global__ __launch_bounds__(64) void fc_kernel(
    const float* __restrict__ g, const float* __restrict__ fcw,
    const float* __restrict__ fcb, float* __restrict__ out) {
  int b = blockIdx.x;
  int f = threadIdx.x;
  __shared__ float gs[64];
  gs[f] = g[b * F_ + f];
  __syncthreads();
  if (f < 10) {
    float s = fcb[f];
    #pragma unroll
    for (int c = 0; c < 64; ++c) s += gs[c] * fcw[c * 10 + f];
    out[b * 10 + f] = s;
  }
}

extern "C" void kernel_launch(void* const* d_in, const int* in_sizes, int n_in,
                              void* d_out, int out_size, void* d_ws, size_t ws_size,
                              hipStream_t stream) {
  const float* x     = (const float*)d_in[0];
  const float* coord = (const float*)d_in[1];
  const float* adj   = (const float*)d_in[2];
  const float* w0    = (const float*)d_in[3];
  const float* root0 = (const float*)d_in[4];
  const float* b0    = (const float*)d_in[5];
  const float* w1    = (const float*)d_in[6];
  const float* root1 = (const float*)d_in[7];
  const float* b1    = (const float*)d_in[8];
  const float* w2    = (const float*)d_in[9];
  const float* root2 = (const float*)d_in[10];
  const float* b2    = (const float*)d_in[11];
  const float* fcw   = (const float*)d_in[12];
  const float* fcb   = (const float*)d_in[13];
  float* out = (float*)d_out;

  char* ws = (char*)d_ws;
  size_t off = 0;
  auto alloc = [&](size_t bytes) {
    void* p = ws + off;
    off = (off + bytes + 255) & ~(size_t)255;
    return p;
  };
  const int R = B_ * N_;  // 16384
  float4* edge    = (float4*)alloc((size_t)R * CAP * 16);
  int4*   cnt4    = (int4*)  alloc((size_t)R * 16);
  float*  deginv  = (float*) alloc((size_t)R * 4);
  _Float16* hx    = (_Float16*)alloc((size_t)R * 128 * 2);   // fp16 x
  _Float16* wt0   = (_Float16*)alloc((size_t)64 * 1280 * 2);
  _Float16* wt1   = (_Float16*)alloc((size_t)64 * 640 * 2);
  _Float16* wt2   = (_Float16*)alloc((size_t)64 * 640 * 2);
  _Float16* sp    = (_Float16*)alloc((size_t)R * 1280 * 2);  // s (max K)
  _Float16* hA    = (_Float16*)alloc((size_t)R * 64 * 2);
  _Float16* hB    = (_Float16*)alloc((size_t)R * 64 * 2);
  unsigned int* gmax = (unsigned int*)alloc((size_t)B_ * F_ * 4);

  preprocess_kernel<<<R, 512, 0, stream>>>(adj, coord, edge, cnt4, deginv, gmax);
  const int PM = R * 32 + 64 * (1280 + 640 + 640);
  prep_misc_kernel<<<(PM + 255) / 256, 256, 0, stream>>>(
      x, hx, w0, root0, w1, root1, w2, root2, wt0, wt1, wt2);

  // layer 0: CIN=128, K = 1280
  gather_kernel<2><<<R, 256, 0, stream>>>(hx, edge, cnt4, deginv, sp);
  gemm_s_kernel<<<R / 64, 256, 0, stream>>>(sp, wt0, b0, hA, nullptr, 1280);

  // layer 1: CIN=64, K = 640
  gather_kernel<1><<<R, 256, 0, stream>>>(hA, edge, cnt4, deginv, sp);
  gemm_s_kernel<<<R / 64, 256, 0, stream>>>(sp, wt1, b1, hB, nullptr, 640);

  // layer 2: CIN=64, K = 640 — fused max-pool
  gather_kernel<1><<<R, 256, 0, stream>>>(hB, edge, cnt4, deginv, sp);
  gemm_s_kernel<<<R / 64, 256, 0, stream>>>(sp, wt2, b2, nullptr, gmax, 640);

  fc_kernel<<<B_, 64, 0, stream>>>((const float*)gmax, fcw, fcb, out);
}

// Round 11
// 255.928 us; speedup vs baseline: 1.7622x; 1.0715x over previous
//
#include <hip/hip_runtime.h>

// SplineCNN on MI355X — aggregate-before-GEMM, L2-direct gather (R6 structure).
//
// Math order: s[n, k*CIN+c] = deginv * sum_{m in N(n)} basis_k(n,m) * h[m,c],
// root column appended -> one dense GEMM per layer:
//   out = relu( [s | h] @ [w; root] + bias ),  K = 10*CIN, N = 64.
// Gather design matrix (measured): LDS-staged edges + unroll-4 + row/wave = best
// (R6, <=41us); global broadcast edge loads = worse (R9, 58us — per-edge VMEM
// serializes); row/block quadrant/wave = worse (R10, 46us — fixed overhead).
// THIS ROUND: the untested cell — LDS-staged edges + UNROLL 8 (8 h-gathers in
// flight per stall group, halving the per-row stall count) at DEFAULT register
// budget (no min-waves launch bound — R8's forced 32 VGPR spilled 205MB).
// h read directly from global (L2-resident, <=512KB/XCD via batch swizzle).
// Quadrant-sorted edge lists give static accumulator targets.
// All tensors fp16 (fp32 accumulate in gather + MFMA); layer-2 GEMM epilogue
// fuses global max-pool via uint-bitcast atomicMax (relu >= 0).

#define B_   32
#define N_   512
#define F_   64
#define CAP  128          // max neighbors per node (mean ~31; P(>128) ~ 18 sigma)

typedef float f32x4 __attribute__((ext_vector_type(4)));
typedef _Float16 f16x8 __attribute__((ext_vector_type(8)));
typedef _Float16 f16x2 __attribute__((ext_vector_type(2)));

// ---------------- preprocess: quadrant-sorted edge lists ----------------
// edge record: float4 { bitcast(m), fx, fy, unused }, sorted by quad = kx0+2*ky0.
// cnt4[row] = per-quadrant counts (clamped to CAP); deginv = 1/clip(deg,1).
// Blocks 0..2047 also zero the pooled-max buffer.
__global__ __launch_bounds__(512) void preprocess_kernel(
    const float* __restrict__ adj, const float* __restrict__ coord,
    float4* __restrict__ edge, int4* __restrict__ cnt4,
    float* __restrict__ deginv, unsigned int* __restrict__ gmax) {
  int row = blockIdx.x;          // b*N + n
  int b = row >> 9;
  int tid = threadIdx.x;         // == m
  int lane = tid & 63, wave = tid >> 6;
  if (row < B_ * F_ && tid == 0) gmax[row] = 0u;
  __shared__ int wc[8][4];
  float a = adj[(size_t)row * N_ + tid];
  bool flag = (a != 0.0f);
  float cxn = coord[(size_t)row * 2 + 0];
  float cyn = coord[(size_t)row * 2 + 1];
  float cxm = coord[(size_t)(b * N_ + tid) * 2 + 0];
  float cym = coord[(size_t)(b * N_ + tid) * 2 + 1];
  float vx = (cxm - cxn + 1.0f);        // = u*2 (K-1 = 2, u in [0,1])
  float vy = (cym - cyn + 1.0f);
  float i0x = fminf(fmaxf(floorf(vx), 0.0f), 1.0f);
  float i0y = fminf(fmaxf(floorf(vy), 0.0f), 1.0f);
  float fx = vx - i0x, fy = vy - i0y;
  int quad = (int)i0x + 2 * (int)i0y;   // 0..3
  unsigned long long bq0 = __ballot(flag && quad == 0);
  unsigned long long bq1 = __ballot(flag && quad == 1);
  unsigned long long bq2 = __ballot(flag && quad == 2);
  unsigned long long bq3 = __ballot(flag && quad == 3);
  if (lane == 0) {
    wc[wave][0] = __popcll(bq0); wc[wave][1] = __popcll(bq1);
    wc[wave][2] = __popcll(bq2); wc[wave][3] = __popcll(bq3);
  }
  __syncthreads();
  int qt0 = 0, qt1 = 0, qt2 = 0, qt3 = 0;
  #pragma unroll
  for (int w2 = 0; w2 < 8; ++w2) {
    qt0 += wc[w2][0]; qt1 += wc[w2][1]; qt2 += wc[w2][2]; qt3 += wc[w2][3];
  }
  if (flag) {
    int off = 0;
    if (quad > 0) off += qt0;
    if (quad > 1) off += qt1;
    if (quad > 2) off += qt2;
    #pragma unroll
    for (int w2 = 0; w2 < 8; ++w2)
      if (w2 < wave) off += wc[w2][quad];
    unsigned long long myb = (quad == 0) ? bq0 : (quad == 1) ? bq1
                           : (quad == 2) ? bq2 : bq3;
    off += __popcll(myb & ((1ULL << lane) - 1ULL));
    if (off < CAP)
      edge[(size_t)row * CAP + off] =
          make_float4(__int_as_float(tid), fx, fy, 1.0f);
  }
  if (tid == 0) {
    int rem = CAP;
    int c0 = min(qt0, rem); rem -= c0;
    int c1 = min(qt1, rem); rem -= c1;
    int c2 = min(qt2, rem); rem -= c2;
    int c3 = min(qt3, rem);
    cnt4[row] = make_int4(c0, c1, c2, c3);
    int total = qt0 + qt1 + qt2 + qt3;
    deginv[row] = 1.0f / (float)(total > 0 ? total : 1);
  }
}

// ---- merged: x fp32->fp16 convert + pack all 3 layers' [w; root] -> Wt fp16 ----
__global__ void prep_misc_kernel(
    const float* __restrict__ x, _Float16* __restrict__ hx,
    const float* __restrict__ w0, const float* __restrict__ root0,
    const float* __restrict__ w1, const float* __restrict__ root1,
    const float* __restrict__ w2, const float* __restrict__ root2,
    _Float16* __restrict__ wt0, _Float16* __restrict__ wt1,
    _Float16* __restrict__ wt2) {
  int idx = blockIdx.x * blockDim.x + threadIdx.x;
  const int CX = B_ * N_ * 32;
  if (idx < CX) {
    float4 v = ((const float4*)x)[idx];
    f16x2 p0, p1;
    p0[0] = (_Float16)v.x; p0[1] = (_Float16)v.y;
    p1[0] = (_Float16)v.z; p1[1] = (_Float16)v.w;
    uint2 u;
    u.x = __builtin_bit_cast(unsigned, p0);
    u.y = __builtin_bit_cast(unsigned, p1);
    ((uint2*)hx)[idx] = u;
    return;
  }
  int r = idx - CX;
  const int S0 = 64 * 1280, S1 = 64 * 640;
  const float *w, *root; _Float16* wt; int KP, CIN;
  if (r < S0)            { w = w0; root = root0; wt = wt0; KP = 1280; CIN = 128; }
  else if (r < S0 + S1)  { w = w1; root = root1; wt = wt1; KP = 640;  CIN = 64;  r -= S0; }
  else if (r < S0 + 2*S1){ w = w2; root = root2; wt = wt2; KP = 640;  CIN = 64;  r -= S0 + S1; }
  else return;
  int f = r / KP, k = r - f * KP;
  int ks = k / CIN, c = k - ks * CIN;
  float v = (ks < 9) ? w[((size_t)ks * CIN + c) * F_ + f]
                     : root[(size_t)c * F_ + f];
  wt[(size_t)f * KP + k] = (_Float16)v;
}

// ---------------- gather: s[row, k*CIN + c] = deginv * sum basis_k * h[m,c] ----------------
// 256 threads = 4 waves, ONE ROW PER WAVE; grid 4096, XCD-swizzled so batch b's
// blocks share an XCD (h slice <=512KB L2-resident). Wave stages its row's edge
// list to LDS (coalesced, <=2 iter), then hot loop: broadcast LDS edge record
// + contiguous 128/256B global h gather (L2 hit) + 4*CH FMAs; UNROLL 8 keeps
// 8 gathers in flight per stall group (R6 had 4). Default VGPR budget — no
// min-waves bound (R8: forced 32 VGPR -> spills). Quadrant runs give static
// accumulator targets. CH = CIN/64 channels per lane.
template<int CH>
__global__ __launch_bounds__(256) void gather_kernel(
    const _Float16* __restrict__ hsrc,   // [16384][CIN] fp16
    const float4* __restrict__ edge, const int4* __restrict__ cnt4,
    const float* __restrict__ deginv,
    _Float16* __restrict__ sp) {         // [16384][KP]
  const int CIN = 64 * CH, KP = 10 * CIN;
  __shared__ float4 esh[4][CAP];
  int wave = threadIdx.x >> 6, lane = threadIdx.x & 63;
  int xcd = blockIdx.x & 7;
  int j = blockIdx.x >> 3;
  int b = xcd * 4 + (j >> 7);
  int n = ((j & 127) << 2) + wave;          // row within batch
  int row = (b << 9) + n;
  int4 c4 = cnt4[row];
  int e1 = c4.x, e2 = e1 + c4.y, e3 = e2 + c4.z, e4 = e3 + c4.w;
  size_t ebase = (size_t)row * CAP;
  for (int i = lane; i < e4; i += 64)
    esh[wave][i] = edge[ebase + i];         // wave-private region, no barrier
  float di = deginv[row];
  const _Float16* hb = hsrc + (size_t)b * N_ * CIN + lane * CH;

  float acc[3][3][CH];
  #pragma unroll
  for (int kx = 0; kx < 3; ++kx)
    #pragma unroll
    for (int ky = 0; ky < 3; ++ky)
      #pragma unroll
      for (int c = 0; c < CH; ++c) acc[kx][ky][c] = 0.0f;

#define EDGE_BODY(E, KX, KY) {                                        \
    float4 er = esh[wave][E];                                         \
    int m = __float_as_int(er.x);                                     \
    float hv[CH];                                                     \
    if (CH == 1) {                                                    \
      hv[0] = (float)hb[(size_t)m * 64];                              \
    } else {                                                          \
      unsigned u = *(const unsigned*)&hb[(size_t)m * 128];            \
      f16x2 hp = __builtin_bit_cast(f16x2, u);                        \
      hv[0] = (float)hp[0]; hv[CH - 1] = (float)hp[1];                \
    }                                                                 \
    float fx = er.y, fy = er.z;                                       \
    float gx = 1.0f - fx, gy = 1.0f - fy;                             \
    float w00 = gx * gy, w01 = gx * fy, w10 = fx * gy, w11 = fx * fy; \
    _Pragma("unroll")                                                 \
    for (int c = 0; c < CH; ++c) {                                    \
      acc[KX][KY][c]         += w00 * hv[c];                          \
      acc[KX][KY + 1][c]     += w01 * hv[c];                          \
      acc[KX + 1][KY][c]     += w10 * hv[c];                          \
      acc[KX + 1][KY + 1][c] += w11 * hv[c];                          \
    } }

  #pragma unroll 8
  for (int e = 0; e < e1; ++e) EDGE_BODY(e, 0, 0)    // quad0: kx0=0, ky0=0
  #pragma unroll 8
  for (int e = e1; e < e2; ++e) EDGE_BODY(e, 1, 0)   // quad1: kx0=1, ky0=0
  #pragma unroll 8
  for (int e = e2; e < e3; ++e) EDGE_BODY(e, 0, 1)   // quad2: kx0=0, ky0=1
  #pragma unroll 8
  for (int e = e3; e < e4; ++e) EDGE_BODY(e, 1, 1)   // quad3: kx0=1, ky0=1
#undef EDGE_BODY

  // store: k = kx*3 + ky (reference reshape order); cols k*CIN + lane*CH
  _Float16* sr = sp + (size_t)row * KP + lane * CH;
  #pragma unroll
  for (int kx = 0; kx < 3; ++kx)
    #pragma unroll
    for (int ky = 0; ky < 3; ++ky) {
      int k = kx * 3 + ky;
      if (CH == 1) {
        sr[(size_t)k * CIN] = (_Float16)(acc[kx][ky][0] * di);
      } else {
        f16x2 p;
        p[0] = (_Float16)(acc[kx][ky][0] * di);
        p[1] = (_Float16)(acc[kx][ky][CH - 1] * di);
        *(f16x2*)&sr[(size_t)k * CIN] = p;
      }
    }
  // root column: h passthrough
  if (CH == 1) {
    sr[(size_t)9 * CIN] = hb[(size_t)n * 64];
  } else {
    *(unsigned*)&sr[(size_t)9 * CIN] = *(const unsigned*)&hb[(size_t)n * 128];
  }
}

// ---------------- dense GEMM: out[m,f] = relu( A[m,:]@Wt[f,:] + bias[f] ) ----------------
// A fp16 [16384][KP], Wt fp16 [64][KP]. M-tile 64 (grid 256), 256 thr = 4 waves,
// wave owns 16 rows x 64 cols, 16x16x32 f16 MFMA. Double-buffered LDS with
// issue-early/write-late staging (T14). Epilogue: fp16 h-out and/or fused
// max-pool (atomicMax on uint bits, relu >= 0).
#define GBK  64
#define GLDK 72
__global__ __launch_bounds__(256) void gemm_s_kernel(
    const _Float16* __restrict__ A, const _Float16* __restrict__ Wt,
    const float* __restrict__ bias, _Float16* __restrict__ hout,
    unsigned int* __restrict__ gmax, int KP) {
  __shared__ __attribute__((aligned(16))) _Float16 As[2][64 * GLDK];
  __shared__ __attribute__((aligned(16))) _Float16 Ws[2][64 * GLDK];
  int bm = blockIdx.x << 6;
  int tid = threadIdx.x, wave = tid >> 6, lane = tid & 63;
  int lr = lane & 15, quad = lane >> 4;
  int srow = tid >> 3, sck = (tid & 7) * 8;       // staging: rows srow, srow+32
  const size_t aoff = (size_t)(bm + srow) * KP + sck;
  const size_t woff = (size_t)srow * KP + sck;

  f32x4 acc[4] = {};
  // stage step 0 directly
  {
    *(float4*)&As[0][srow * GLDK + sck]        = *(const float4*)&A[aoff];
    *(float4*)&As[0][(srow + 32) * GLDK + sck] = *(const float4*)&A[aoff + (size_t)32 * KP];
    *(float4*)&Ws[0][srow * GLDK + sck]        = *(const float4*)&Wt[woff];
    *(float4*)&Ws[0][(srow + 32) * GLDK + sck] = *(const float4*)&Wt[woff + (size_t)32 * KP];
  }
  int S = KP / GBK, cur = 0;
  float4 pa0, pa1, pw0, pw1;
  for (int s = 0; s < S; ++s) {
    if (s + 1 < S) {                 // issue next tile's loads (no wait)
      int k0 = (s + 1) * GBK;
      pa0 = *(const float4*)&A[aoff + k0];
      pa1 = *(const float4*)&A[aoff + (size_t)32 * KP + k0];
      pw0 = *(const float4*)&Wt[woff + k0];
      pw1 = *(const float4*)&Wt[woff + (size_t)32 * KP + k0];
    }
    __syncthreads();                 // buf[cur] ready for all waves
    #pragma unroll
    for (int kk = 0; kk < GBK; kk += 32) {
      f16x8 af = *(const f16x8*)&As[cur][(16 * wave + lr) * GLDK + kk + quad * 8];
      #pragma unroll
      for (int j = 0; j < 4; ++j) {
        f16x8 bf = *(const f16x8*)&Ws[cur][(16 * j + lr) * GLDK + kk + quad * 8];
        acc[j] = __builtin_amdgcn_mfma_f32_16x16x32_f16(af, bf, acc[j], 0, 0, 0);
      }
    }
    if (s + 1 < S) {                 // write-late into the other buffer
      int nb = cur ^ 1;
      *(float4*)&As[nb][srow * GLDK + sck]        = pa0;
      *(float4*)&As[nb][(srow + 32) * GLDK + sck] = pa1;
      *(float4*)&Ws[nb][srow * GLDK + sck]        = pw0;
      *(float4*)&Ws[nb][(srow + 32) * GLDK + sck] = pw1;
    }
    cur ^= 1;
  }
  // epilogue: C layout col = lane&15, row = quad*4 + r (verified)
  int b = bm >> 9;
  #pragma unroll
  for (int j = 0; j < 4; ++j) {
    int f = 16 * j + lr;
    float bs = bias[f];
    float vmax = 0.0f;
    #pragma unroll
    for (int r = 0; r < 4; ++r) {
      int m = bm + (wave << 4) + (quad << 2) + r;
      float v = fmaxf(acc[j][r] + bs, 0.0f);
      if (hout) hout[(size_t)m * F_ + f] = (_Float16)v;
      vmax = fmaxf(vmax, v);
    }
    if (gmax) atomicMax(&gmax[(b << 6) + f], __float_as_uint(vmax));
  }
}

// ---------------- FC from pooled features ----------------
__global__ __launch_bounds__(64) void fc_kernel(
    const float* __restrict__ g, const float* __restrict__ fcw,
    const float* __restrict__ fcb, float* __restrict__ out) {
  int b = blockIdx.x;
  int f = threadIdx.x;
  __shared__ float gs[64];
  gs[f] = g[b * F_ + f];
  __syncthreads();
  if (f < 10) {
    float s = fcb[f];
    #pragma unroll
    for (int c = 0; c < 64; ++c) s += gs[c] * fcw[c * 10 + f];
    out[b * 10 + f] = s;
  }
}

extern "C" void kernel_launch(void* const* d_in, const int* in_sizes, int n_in,
                              void* d_out, int out_size, void* d_ws, size_t ws_size,
                              hipStream_t stream) {
  const float* x     = (const float*)d_in[0];
  const float* coord = (const float*)d_in[1];
  const float* adj   = (const float*)d_in[2];
  const float* w0    = (const float*)d_in[3];
  const float* root0 = (const float*)d_in[4];
  const float* b0    = (const float*)d_in[5];
  const float* w1    = (const float*)d_in[6];
  const float* root1 = (const float*)d_in[7];
  const float* b1    = (const float*)d_in[8];
  const float* w2    = (const float*)d_in[9];
  const float* root2 = (const float*)d_in[10];
  const float* b2    = (const float*)d_in[11];
  const float* fcw   = (const float*)d_in[12];
  const float* fcb   = (const float*)d_in[13];
  float* out = (float*)d_out;

  char* ws = (char*)d_ws;
  size_t off = 0;
  auto alloc = [&](size_t bytes) {
    void* p = ws + off;
    off = (off + bytes + 255) & ~(size_t)255;
    return p;
  };
  const int R = B_ * N_;  // 16384
  float4* edge    = (float4*)alloc((size_t)R * CAP * 16);
  int4*   cnt4    = (int4*)  alloc((size_t)R * 16);
  float*  deginv  = (float*) alloc((size_t)R * 4);
  _Float16* hx    = (_Float16*)alloc((size_t)R * 128 * 2);   // fp16 x
  _Float16* wt0   = (_Float16*)alloc((size_t)64 * 1280 * 2);
  _Float16* wt1   = (_Float16*)alloc((size_t)64 * 640 * 2);
  _Float16* wt2   = (_Float16*)alloc((size_t)64 * 640 * 2);
  _Float16* sp    = (_Float16*)alloc((size_t)R * 1280 * 2);  // s (max K)
  _Float16* hA    = (_Float16*)alloc((size_t)R * 64 * 2);
  _Float16* hB    = (_Float16*)alloc((size_t)R * 64 * 2);
  unsigned int* gmax = (unsigned int*)alloc((size_t)B_ * F_ * 4);

  preprocess_kernel<<<R, 512, 0, stream>>>(adj, coord, edge, cnt4, deginv, gmax);
  const int PM = R * 32 + 64 * (1280 + 640 + 640);
  prep_misc_kernel<<<(PM + 255) / 256, 256, 0, stream>>>(
      x, hx, w0, root0, w1, root1, w2, root2, wt0, wt1, wt2);

  // layer 0: CIN=128, K = 1280
  gather_kernel<2><<<R / 4, 256, 0, stream>>>(hx, edge, cnt4, deginv, sp);
  gemm_s_kernel<<<R / 64, 256, 0, stream>>>(sp, wt0, b0, hA, nullptr, 1280);

  // layer 1: CIN=64, K = 640
  gather_kernel<1><<<R / 4, 256, 0, stream>>>(hA, edge, cnt4, deginv, sp);
  gemm_s_kernel<<<R / 64, 256, 0, stream>>>(sp, wt1, b1, hB, nullptr, 640);

  // layer 2: CIN=64, K = 640 — fused max-pool
  gather_kernel<1><<<R / 4, 256, 0, stream>>>(hB, edge, cnt4, deginv, sp);
  gemm_s_kernel<<<R / 64, 256, 0, stream>>>(sp, wt2, b2, nullptr, gmax, 640);

  fc_kernel<<<B_, 64, 0, stream>>>((const float*)gmax, fcw, fcb, out);
}

// Round 12
// 247.725 us; speedup vs baseline: 1.8206x; 1.0331x over previous
//
#include <hip/hip_runtime.h>

// SplineCNN on MI355X — aggregate-before-GEMM; slot-parallel gather (4 edges/VMEM).
//
// Math order: s[n, k*CIN+c] = deginv * sum_{m in N(n)} basis_k(n,m) * h[m,c],
// root column appended -> one dense GEMM per layer:
//   out = relu( [s | h] @ [w; root] + bias ),  K = 10*CIN, N = 64.
// Evidence R6-R11: gather is latency-bound at ~40us/layer, invariant to bytes/
// staging/unroll/wave-decomposition. Common factor: ONE VMEM instruction per
// edge. THIS ROUND: wave = 4 edge-slots x 16 lanes; one load instruction
// fetches FOUR edges' h rows (4x fewer VMEM instructions, 4x MLP per issue,
// ~2x less VALU: weights computed once per edge, not per lane). Preprocess
// pads each quadrant run to x4 with zero records (er.w=0 -> all tap weights 0)
// so groups are quadrant-uniform -> static accumulator targets. Once-per-row
// cross-slot shfl_xor(16/32) reduce; slot-0 lanes store fp16. Edge lists
// LDS-staged (R6-proven); h read L2-direct (batch-XCD swizzle). Default VGPR
// budget (R8: forced bounds -> spills).
// All tensors fp16 (fp32 accumulate in gather + MFMA); layer-2 GEMM epilogue
// fuses global max-pool via uint-bitcast atomicMax (relu >= 0).

#define B_   32
#define N_   512
#define F_   64
#define CAP  128          // max padded neighbors per node (mean ~31 + <=12 pad)

typedef float f32x4 __attribute__((ext_vector_type(4)));
typedef _Float16 f16x8 __attribute__((ext_vector_type(8)));
typedef _Float16 f16x2 __attribute__((ext_vector_type(2)));

// ---------------- preprocess: quadrant-sorted, x4-padded edge lists ----------------
// edge record: float4 { bitcast(m), fx, fy, 1.0 } valid; all-zero = pad (weights 0).
// cnt4[row] = PADDED per-quadrant counts (each x4, cumulative <= CAP);
// deginv = 1/clip(true_deg,1). Blocks 0..2047 also zero the pooled-max buffer.
__global__ __launch_bounds__(512) void preprocess_kernel(
    const float* __restrict__ adj, const float* __restrict__ coord,
    float4* __restrict__ edge, int4* __restrict__ cnt4,
    float* __restrict__ deginv, unsigned int* __restrict__ gmax) {
  int row = blockIdx.x;          // b*N + n
  int b = row >> 9;
  int tid = threadIdx.x;         // == m
  int lane = tid & 63, wave = tid >> 6;
  if (row < B_ * F_ && tid == 0) gmax[row] = 0u;
  __shared__ int wc[8][4];
  float a = adj[(size_t)row * N_ + tid];
  bool flag = (a != 0.0f);
  float cxn = coord[(size_t)row * 2 + 0];
  float cyn = coord[(size_t)row * 2 + 1];
  float cxm = coord[(size_t)(b * N_ + tid) * 2 + 0];
  float cym = coord[(size_t)(b * N_ + tid) * 2 + 1];
  float vx = (cxm - cxn + 1.0f);        // = u*2 (K-1 = 2, u in [0,1])
  float vy = (cym - cyn + 1.0f);
  float i0x = fminf(fmaxf(floorf(vx), 0.0f), 1.0f);
  float i0y = fminf(fmaxf(floorf(vy), 0.0f), 1.0f);
  float fx = vx - i0x, fy = vy - i0y;
  int quad = (int)i0x + 2 * (int)i0y;   // 0..3
  unsigned long long bq0 = __ballot(flag && quad == 0);
  unsigned long long bq1 = __ballot(flag && quad == 1);
  unsigned long long bq2 = __ballot(flag && quad == 2);
  unsigned long long bq3 = __ballot(flag && quad == 3);
  if (lane == 0) {
    wc[wave][0] = __popcll(bq0); wc[wave][1] = __popcll(bq1);
    wc[wave][2] = __popcll(bq2); wc[wave][3] = __popcll(bq3);
  }
  __syncthreads();
  int qt0 = 0, qt1 = 0, qt2 = 0, qt3 = 0;
  #pragma unroll
  for (int w2 = 0; w2 < 8; ++w2) {
    qt0 += wc[w2][0]; qt1 += wc[w2][1]; qt2 += wc[w2][2]; qt3 += wc[w2][3];
  }
  // padded layout (rem stays a multiple of 4)
  int rem = CAP;
  int c0 = min(qt0, rem); int c0p = min((c0 + 3) & ~3, rem); c0 = min(c0, c0p); rem -= c0p;
  int c1 = min(qt1, rem); int c1p = min((c1 + 3) & ~3, rem); c1 = min(c1, c1p); rem -= c1p;
  int c2 = min(qt2, rem); int c2p = min((c2 + 3) & ~3, rem); c2 = min(c2, c2p); rem -= c2p;
  int c3 = min(qt3, rem); int c3p = min((c3 + 3) & ~3, rem); c3 = min(c3, c3p);
  int B1 = c0p, B2 = c0p + c1p, B3 = c0p + c1p + c2p;
  if (flag) {
    int offq = 0;
    #pragma unroll
    for (int w2 = 0; w2 < 8; ++w2)
      if (w2 < wave) offq += wc[w2][quad];
    unsigned long long myb = (quad == 0) ? bq0 : (quad == 1) ? bq1
                           : (quad == 2) ? bq2 : bq3;
    offq += __popcll(myb & ((1ULL << lane) - 1ULL));
    int base = (quad == 0) ? 0 : (quad == 1) ? B1 : (quad == 2) ? B2 : B3;
    int clim = (quad == 0) ? c0 : (quad == 1) ? c1 : (quad == 2) ? c2 : c3;
    if (offq < clim)
      edge[(size_t)row * CAP + base + offq] =
          make_float4(__int_as_float(tid), fx, fy, 1.0f);
  }
  if (tid < 4) {     // zero-fill pad slots (<=3 per quadrant)
    int q = tid;
    int cq  = (q == 0) ? c0  : (q == 1) ? c1  : (q == 2) ? c2  : c3;
    int cqp = (q == 0) ? c0p : (q == 1) ? c1p : (q == 2) ? c2p : c3p;
    int Bq  = (q == 0) ? 0   : (q == 1) ? B1  : (q == 2) ? B2  : B3;
    for (int i = cq; i < cqp; ++i)
      edge[(size_t)row * CAP + Bq + i] = make_float4(0.f, 0.f, 0.f, 0.f);
  }
  if (tid == 0) {
    cnt4[row] = make_int4(c0p, c1p, c2p, c3p);
    int total = qt0 + qt1 + qt2 + qt3;
    deginv[row] = 1.0f / (float)(total > 0 ? total : 1);
  }
}

// ---- merged: x fp32->fp16 convert + pack all 3 layers' [w; root] -> Wt fp16 ----
__global__ void prep_misc_kernel(
    const float* __restrict__ x, _Float16* __restrict__ hx,
    const float* __restrict__ w0, const float* __restrict__ root0,
    const float* __restrict__ w1, const float* __restrict__ root1,
    const float* __restrict__ w2, const float* __restrict__ root2,
    _Float16* __restrict__ wt0, _Float16* __restrict__ wt1,
    _Float16* __restrict__ wt2) {
  int idx = blockIdx.x * blockDim.x + threadIdx.x;
  const int CX = B_ * N_ * 32;
  if (idx < CX) {
    float4 v = ((const float4*)x)[idx];
    f16x2 p0, p1;
    p0[0] = (_Float16)v.x; p0[1] = (_Float16)v.y;
    p1[0] = (_Float16)v.z; p1[1] = (_Float16)v.w;
    uint2 u;
    u.x = __builtin_bit_cast(unsigned, p0);
    u.y = __builtin_bit_cast(unsigned, p1);
    ((uint2*)hx)[idx] = u;
    return;
  }
  int r = idx - CX;
  const int S0 = 64 * 1280, S1 = 64 * 640;
  const float *w, *root; _Float16* wt; int KP, CIN;
  if (r < S0)            { w = w0; root = root0; wt = wt0; KP = 1280; CIN = 128; }
  else if (r < S0 + S1)  { w = w1; root = root1; wt = wt1; KP = 640;  CIN = 64;  r -= S0; }
  else if (r < S0 + 2*S1){ w = w2; root = root2; wt = wt2; KP = 640;  CIN = 64;  r -= S0 + S1; }
  else return;
  int f = r / KP, k = r - f * KP;
  int ks = k / CIN, c = k - ks * CIN;
  float v = (ks < 9) ? w[((size_t)ks * CIN + c) * F_ + f]
                     : root[(size_t)c * F_ + f];
  wt[(size_t)f * KP + k] = (_Float16)v;
}

// ---------------- gather: slot-parallel, 4 edges per VMEM instruction ----------------
// 256 threads = 4 waves, one row per wave; grid R/4, XCD-swizzled (batch b on
// XCD b>>2, h slice L2-resident). Lane = (slot = lane>>4, chan-group =
// (lane&15)*CPL). Per 4-edge group (quadrant-uniform thanks to padding): one
// ds_read_b128 (er, broadcast within slot) + ONE global load fetching all 4
// edges' h (slot picks the edge) + static 2x2 FMA targets. Cross-slot
// shfl_xor(16/32) reduce once per row; slot-0 lanes store fp16 (+root).
// CPL = CIN/16 channels per lane (4 or 8).
template<int CPL>
__global__ __launch_bounds__(256) void gather_kernel(
    const _Float16* __restrict__ hsrc,   // [16384][CIN] fp16
    const float4* __restrict__ edge, const int4* __restrict__ cnt4,
    const float* __restrict__ deginv,
    _Float16* __restrict__ sp) {         // [16384][KP]
  const int CIN = 16 * CPL, KP = 10 * CIN;
  __shared__ float4 esh[4][CAP];
  int wave = threadIdx.x >> 6, lane = threadIdx.x & 63;
  int slot = lane >> 4;                    // edge slot 0..3
  int cg = (lane & 15) * CPL;              // channel group base
  int xcd = blockIdx.x & 7;
  int j = blockIdx.x >> 3;
  int b = xcd * 4 + (j >> 7);
  int n = ((j & 127) << 2) + wave;         // row within batch
  int row = (b << 9) + n;
  int4 c4 = cnt4[row];                     // padded counts (x4 each)
  int e1 = c4.x, e2 = e1 + c4.y, e3 = e2 + c4.z, e4 = e3 + c4.w;
  size_t ebase = (size_t)row * CAP;
  for (int i = lane; i < e4; i += 64)
    esh[wave][i] = edge[ebase + i];        // wave-private region, no barrier
  float di = deginv[row];
  const _Float16* hb = hsrc + (size_t)b * N_ * CIN + cg;

  float acc[3][3][CPL] = {};

#define GRP(G, KX, KY) {                                              \
    float4 er = esh[wave][(G) + slot];                                \
    int m = __float_as_int(er.x);                                     \
    float fx = er.y, fy = er.z, vv = er.w;                            \
    float gx = vv - fx, gy = vv - fy;   /* pad: vv=0 -> all w = 0 */  \
    float w00 = gx * gy, w01 = gx * fy, w10 = fx * gy, w11 = fx * fy; \
    _Float16 hr[CPL];                                                 \
    if (CPL == 4) *(uint2*)hr = *(const uint2*)&hb[(size_t)m * CIN];  \
    else          *(uint4*)hr = *(const uint4*)&hb[(size_t)m * CIN];  \
    _Pragma("unroll")                                                 \
    for (int c = 0; c < CPL; ++c) {                                   \
      float hv = (float)hr[c];                                        \
      acc[KX][KY][c]         += w00 * hv;                             \
      acc[KX][KY + 1][c]     += w01 * hv;                             \
      acc[KX + 1][KY][c]     += w10 * hv;                             \
      acc[KX + 1][KY + 1][c] += w11 * hv;                             \
    } }

  #pragma unroll 2
  for (int g = 0; g < e1; g += 4) GRP(g, 0, 0)    // quad0: kx0=0, ky0=0
  #pragma unroll 2
  for (int g = e1; g < e2; g += 4) GRP(g, 1, 0)   // quad1: kx0=1, ky0=0
  #pragma unroll 2
  for (int g = e2; g < e3; g += 4) GRP(g, 0, 1)   // quad2: kx0=0, ky0=1
  #pragma unroll 2
  for (int g = e3; g < e4; g += 4) GRP(g, 1, 1)   // quad3: kx0=1, ky0=1
#undef GRP

  // cross-slot reduce (slots differ in lane bits 4,5) + store by slot 0
  _Float16* sr = sp + (size_t)row * KP + cg;
  #pragma unroll
  for (int kx = 0; kx < 3; ++kx)
    #pragma unroll
    for (int ky = 0; ky < 3; ++ky) {
      int k = kx * 3 + ky;
      _Float16 o[CPL];
      #pragma unroll
      for (int c = 0; c < CPL; ++c) {
        float v = acc[kx][ky][c];
        v += __shfl_xor(v, 16);
        v += __shfl_xor(v, 32);
        o[c] = (_Float16)(v * di);
      }
      if (slot == 0) {
        if (CPL == 4) *(uint2*)&sr[(size_t)k * CIN] = *(uint2*)o;
        else          *(uint4*)&sr[(size_t)k * CIN] = *(uint4*)o;
      }
    }
  if (slot == 0) {   // root column: h passthrough
    if (CPL == 4)
      *(uint2*)&sr[(size_t)9 * CIN] = *(const uint2*)&hb[(size_t)n * CIN];
    else
      *(uint4*)&sr[(size_t)9 * CIN] = *(const uint4*)&hb[(size_t)n * CIN];
  }
}

// ---------------- dense GEMM: out[m,f] = relu( A[m,:]@Wt[f,:] + bias[f] ) ----------------
// A fp16 [16384][KP], Wt fp16 [64][KP]. M-tile 64 (grid 256), 256 thr = 4 waves,
// wave owns 16 rows x 64 cols, 16x16x32 f16 MFMA. Double-buffered LDS with
// issue-early/write-late staging (T14). Epilogue: fp16 h-out and/or fused
// max-pool (atomicMax on uint bits, relu >= 0).
#define GBK  64
#define GLDK 72
__global__ __launch_bounds__(256) void gemm_s_kernel(
    const _Float16* __restrict__ A, const _Float16* __restrict__ Wt,
    const float* __restrict__ bias, _Float16* __restrict__ hout,
    unsigned int* __restrict__ gmax, int KP) {
  __shared__ __attribute__((aligned(16))) _Float16 As[2][64 * GLDK];
  __shared__ __attribute__((aligned(16))) _Float16 Ws[2][64 * GLDK];
  int bm = blockIdx.x << 6;
  int tid = threadIdx.x, wave = tid >> 6, lane = tid & 63;
  int lr = lane & 15, quad = lane >> 4;
  int srow = tid >> 3, sck = (tid & 7) * 8;       // staging: rows srow, srow+32
  const size_t aoff = (size_t)(bm + srow) * KP + sck;
  const size_t woff = (size_t)srow * KP + sck;

  f32x4 acc[4] = {};
  // stage step 0 directly
  {
    *(float4*)&As[0][srow * GLDK + sck]        = *(const float4*)&A[aoff];
    *(float4*)&As[0][(srow + 32) * GLDK + sck] = *(const float4*)&A[aoff + (size_t)32 * KP];
    *(float4*)&Ws[0][srow * GLDK + sck]        = *(const float4*)&Wt[woff];
    *(float4*)&Ws[0][(srow + 32) * GLDK + sck] = *(const float4*)&Wt[woff + (size_t)32 * KP];
  }
  int S = KP / GBK, cur = 0;
  float4 pa0, pa1, pw0, pw1;
  for (int s = 0; s < S; ++s) {
    if (s + 1 < S) {                 // issue next tile's loads (no wait)
      int k0 = (s + 1) * GBK;
      pa0 = *(const float4*)&A[aoff + k0];
      pa1 = *(const float4*)&A[aoff + (size_t)32 * KP + k0];
      pw0 = *(const float4*)&Wt[woff + k0];
      pw1 = *(const float4*)&Wt[woff + (size_t)32 * KP + k0];
    }
    __syncthreads();                 // buf[cur] ready for all waves
    #pragma unroll
    for (int kk = 0; kk < GBK; kk += 32) {
      f16x8 af = *(const f16x8*)&As[cur][(16 * wave + lr) * GLDK + kk + quad * 8];
      #pragma unroll
      for (int j = 0; j < 4; ++j) {
        f16x8 bf = *(const f16x8*)&Ws[cur][(16 * j + lr) * GLDK + kk + quad * 8];
        acc[j] = __builtin_amdgcn_mfma_f32_16x16x32_f16(af, bf, acc[j], 0, 0, 0);
      }
    }
    if (s + 1 < S) {                 // write-late into the other buffer
      int nb = cur ^ 1;
      *(float4*)&As[nb][srow * GLDK + sck]        = pa0;
      *(float4*)&As[nb][(srow + 32) * GLDK + sck] = pa1;
      *(float4*)&Ws[nb][srow * GLDK + sck]        = pw0;
      *(float4*)&Ws[nb][(srow + 32) * GLDK + sck] = pw1;
    }
    cur ^= 1;
  }
  // epilogue: C layout col = lane&15, row = quad*4 + r (verified)
  int b = bm >> 9;
  #pragma unroll
  for (int j = 0; j < 4; ++j) {
    int f = 16 * j + lr;
    float bs = bias[f];
    float vmax = 0.0f;
    #pragma unroll
    for (int r = 0; r < 4; ++r) {
      int m = bm + (wave << 4) + (quad << 2) + r;
      float v = fmaxf(acc[j][r] + bs, 0.0f);
      if (hout) hout[(size_t)m * F_ + f] = (_Float16)v;
      vmax = fmaxf(vmax, v);
    }
    if (gmax) atomicMax(&gmax[(b << 6) + f], __float_as_uint(vmax));
  }
}

// ---------------- FC from pooled features ----------------
__global__ __launch_bounds__(64) void fc_kernel(
    const float* __restrict__ g, const float* __restrict__ fcw,
    const float* __restrict__ fcb, float* __restrict__ out) {
  int b = blockIdx.x;
  int f = threadIdx.x;
  __shared__ float gs[64];
  gs[f] = g[b * F_ + f];
  __syncthreads();
  if (f < 10) {
    float s = fcb[f];
    #pragma unroll
    for (int c = 0; c < 64; ++c) s += gs[c] * fcw[c * 10 + f];
    out[b * 10 + f] = s;
  }
}

extern "C" void kernel_launch(void* const* d_in, const int* in_sizes, int n_in,
                              void* d_out, int out_size, void* d_ws, size_t ws_size,
                              hipStream_t stream) {
  const float* x     = (const float*)d_in[0];
  const float* coord = (const float*)d_in[1];
  const float* adj   = (const float*)d_in[2];
  const float* w0    = (const float*)d_in[3];
  const float* root0 = (const float*)d_in[4];
  const float* b0    = (const float*)d_in[5];
  const float* w1    = (const float*)d_in[6];
  const float* root1 = (const float*)d_in[7];
  const float* b1    = (const float*)d_in[8];
  const float* w2    = (const float*)d_in[9];
  const float* root2 = (const float*)d_in[10];
  const float* b2    = (const float*)d_in[11];
  const float* fcw   = (const float*)d_in[12];
  const float* fcb   = (const float*)d_in[13];
  float* out = (float*)d_out;

  char* ws = (char*)d_ws;
  size_t off = 0;
  auto alloc = [&](size_t bytes) {
    void* p = ws + off;
    off = (off + bytes + 255) & ~(size_t)255;
    return p;
  };
  const int R = B_ * N_;  // 16384
  float4* edge    = (float4*)alloc((size_t)R * CAP * 16);
  int4*   cnt4    = (int4*)  alloc((size_t)R * 16);
  float*  deginv  = (float*) alloc((size_t)R * 4);
  _Float16* hx    = (_Float16*)alloc((size_t)R * 128 * 2);   // fp16 x
  _Float16* wt0   = (_Float16*)alloc((size_t)64 * 1280 * 2);
  _Float16* wt1   = (_Float16*)alloc((size_t)64 * 640 * 2);
  _Float16* wt2   = (_Float16*)alloc((size_t)64 * 640 * 2);
  _Float16* sp    = (_Float16*)alloc((size_t)R * 1280 * 2);  // s (max K)
  _Float16* hA    = (_Float16*)alloc((size_t)R * 64 * 2);
  _Float16* hB    = (_Float16*)alloc((size_t)R * 64 * 2);
  unsigned int* gmax = (unsigned int*)alloc((size_t)B_ * F_ * 4);

  preprocess_kernel<<<R, 512, 0, stream>>>(adj, coord, edge, cnt4, deginv, gmax);
  const int PM = R * 32 + 64 * (1280 + 640 + 640);
  prep_misc_kernel<<<(PM + 255) / 256, 256, 0, stream>>>(
      x, hx, w0, root0, w1, root1, w2, root2, wt0, wt1, wt2);

  // layer 0: CIN=128 (CPL=8), K = 1280
  gather_kernel<8><<<R / 4, 256, 0, stream>>>(hx, edge, cnt4, deginv, sp);
  gemm_s_kernel<<<R / 64, 256, 0, stream>>>(sp, wt0, b0, hA, nullptr, 1280);

  // layer 1: CIN=64 (CPL=4), K = 640
  gather_kernel<4><<<R / 4, 256, 0, stream>>>(hA, edge, cnt4, deginv, sp);
  gemm_s_kernel<<<R / 64, 256, 0, stream>>>(sp, wt1, b1, hB, nullptr, 640);

  // layer 2: CIN=64 (CPL=4), K = 640 — fused max-pool
  gather_kernel<4><<<R / 4, 256, 0, stream>>>(hB, edge, cnt4, deginv, sp);
  gemm_s_kernel<<<R / 64, 256, 0, stream>>>(sp, wt2, b2, nullptr, gmax, 640);

  fc_kernel<<<B_, 64, 0, stream>>>((const float*)gmax, fcw, fcb, out);
}

// Round 13
// 235.214 us; speedup vs baseline: 1.9174x; 1.0532x over previous
//
#include <hip/hip_runtime.h>

// SplineCNN on MI355X — aggregate-before-GEMM, L2-direct gather (R6 structure).
//
// Math order: s[n, k*CIN+c] = deginv * sum_{m in N(n)} basis_k(n,m) * h[m,c],
// root column appended -> one dense GEMM per layer:
//   out = relu( [s | h] @ [w; root] + bias ),  K = 10*CIN, N = 64.
// Gather evidence R6-R12: ~40us/layer, invariant to bytes/staging/unroll/wave
// decomposition. R11 counter explains it: VGPR_Count=68 — just past the 64-VGPR
// occupancy step (<=64 -> 8 waves/SIMD; 65-128 -> 4) -> gather capped at 50%
// occupancy, latency unhidable. THIS ROUND: exact R6 gather (unroll 4, lean
// body, live ~50 VGPR) + __launch_bounds__(256,8) to cross the cliff. R8's
// spill disaster was the FAT unroll-8 body at this bound; the lean body fits.
// Also: prep (x->fp16 + weight pack) folded into preprocess (-1 dispatch).
// h read L2-direct (batch-XCD swizzle, slice <=512KB); edge lists LDS-staged.
// All tensors fp16 (fp32 accumulate in gather + MFMA); layer-2 GEMM epilogue
// fuses global max-pool via uint-bitcast atomicMax (relu >= 0).

#define B_   32
#define N_   512
#define F_   64
#define CAP  128          // max neighbors per node (mean ~31; P(>128) ~ 18 sigma)

typedef float f32x4 __attribute__((ext_vector_type(4)));
typedef _Float16 f16x8 __attribute__((ext_vector_type(8)));
typedef _Float16 f16x2 __attribute__((ext_vector_type(2)));

// ---------------- preprocess: quadrant-sorted edge lists + merged prep ----------------
// edge record: float4 { bitcast(m), fx, fy, unused }, sorted by quad = kx0+2*ky0.
// cnt4[row] = per-quadrant counts (clamped to CAP); deginv = 1/clip(deg,1).
// Blocks 0..2047 zero the pooled-max buffer. First 1344 blocks also run the
// merged prep work: x fp32->fp16 (4 elems/thread) + pack [w;root] -> Wt fp16.
__global__ __launch_bounds__(512) void preprocess_kernel(
    const float* __restrict__ adj, const float* __restrict__ coord,
    float4* __restrict__ edge, int4* __restrict__ cnt4,
    float* __restrict__ deginv, unsigned int* __restrict__ gmax,
    const float* __restrict__ x, _Float16* __restrict__ hx,
    const float* __restrict__ w0, const float* __restrict__ root0,
    const float* __restrict__ w1, const float* __restrict__ root1,
    const float* __restrict__ w2, const float* __restrict__ root2,
    _Float16* __restrict__ wt0, _Float16* __restrict__ wt1,
    _Float16* __restrict__ wt2) {
  int row = blockIdx.x;          // b*N + n
  int b = row >> 9;
  int tid = threadIdx.x;         // == m
  int lane = tid & 63, wave = tid >> 6;
  if (row < B_ * F_ && tid == 0) gmax[row] = 0u;

  // ---- merged prep: idx space [0, R*32) convx; then packw for 3 layers ----
  {
    int idx = row * 512 + tid;
    const int CX = B_ * N_ * 32;
    const int S0 = 64 * 1280, S1 = 64 * 640;
    if (idx < CX) {
      float4 v = ((const float4*)x)[idx];
      f16x2 p0, p1;
      p0[0] = (_Float16)v.x; p0[1] = (_Float16)v.y;
      p1[0] = (_Float16)v.z; p1[1] = (_Float16)v.w;
      uint2 u;
      u.x = __builtin_bit_cast(unsigned, p0);
      u.y = __builtin_bit_cast(unsigned, p1);
      ((uint2*)hx)[idx] = u;
    } else if (idx < CX + S0 + 2 * S1) {
      int r = idx - CX;
      const float *w, *root; _Float16* wt; int KP, CIN;
      if (r < S0)           { w = w0; root = root0; wt = wt0; KP = 1280; CIN = 128; }
      else if (r < S0 + S1) { w = w1; root = root1; wt = wt1; KP = 640;  CIN = 64;  r -= S0; }
      else                  { w = w2; root = root2; wt = wt2; KP = 640;  CIN = 64;  r -= S0 + S1; }
      int f = r / KP, k = r - f * KP;
      int ks = k / CIN, c = k - ks * CIN;
      float v = (ks < 9) ? w[((size_t)ks * CIN + c) * F_ + f]
                         : root[(size_t)c * F_ + f];
      wt[(size_t)f * KP + k] = (_Float16)v;
    }
  }

  __shared__ int wc[8][4];
  float a = adj[(size_t)row * N_ + tid];
  bool flag = (a != 0.0f);
  float cxn = coord[(size_t)row * 2 + 0];
  float cyn = coord[(size_t)row * 2 + 1];
  float cxm = coord[(size_t)(b * N_ + tid) * 2 + 0];
  float cym = coord[(size_t)(b * N_ + tid) * 2 + 1];
  float vx = (cxm - cxn + 1.0f);        // = u*2 (K-1 = 2, u in [0,1])
  float vy = (cym - cyn + 1.0f);
  float i0x = fminf(fmaxf(floorf(vx), 0.0f), 1.0f);
  float i0y = fminf(fmaxf(floorf(vy), 0.0f), 1.0f);
  float fx = vx - i0x, fy = vy - i0y;
  int quad = (int)i0x + 2 * (int)i0y;   // 0..3
  unsigned long long bq0 = __ballot(flag && quad == 0);
  unsigned long long bq1 = __ballot(flag && quad == 1);
  unsigned long long bq2 = __ballot(flag && quad == 2);
  unsigned long long bq3 = __ballot(flag && quad == 3);
  if (lane == 0) {
    wc[wave][0] = __popcll(bq0); wc[wave][1] = __popcll(bq1);
    wc[wave][2] = __popcll(bq2); wc[wave][3] = __popcll(bq3);
  }
  __syncthreads();
  int qt0 = 0, qt1 = 0, qt2 = 0, qt3 = 0;
  #pragma unroll
  for (int w2 = 0; w2 < 8; ++w2) {
    qt0 += wc[w2][0]; qt1 += wc[w2][1]; qt2 += wc[w2][2]; qt3 += wc[w2][3];
  }
  if (flag) {
    int off = 0;
    if (quad > 0) off += qt0;
    if (quad > 1) off += qt1;
    if (quad > 2) off += qt2;
    #pragma unroll
    for (int w2 = 0; w2 < 8; ++w2)
      if (w2 < wave) off += wc[w2][quad];
    unsigned long long myb = (quad == 0) ? bq0 : (quad == 1) ? bq1
                           : (quad == 2) ? bq2 : bq3;
    off += __popcll(myb & ((1ULL << lane) - 1ULL));
    if (off < CAP)
      edge[(size_t)row * CAP + off] =
          make_float4(__int_as_float(tid), fx, fy, 1.0f);
  }
  if (tid == 0) {
    int rem = CAP;
    int c0 = min(qt0, rem); rem -= c0;
    int c1 = min(qt1, rem); rem -= c1;
    int c2 = min(qt2, rem); rem -= c2;
    int c3 = min(qt3, rem);
    cnt4[row] = make_int4(c0, c1, c2, c3);
    int total = qt0 + qt1 + qt2 + qt3;
    deginv[row] = 1.0f / (float)(total > 0 ? total : 1);
  }
}

// ---------------- gather: s[row, k*CIN + c] = deginv * sum basis_k * h[m,c] ----------------
// 256 threads = 4 waves, ONE ROW PER WAVE; grid 4096, XCD-swizzled so batch b's
// blocks share an XCD (h slice <=512KB L2-resident). Wave stages its row's edge
// list to LDS (coalesced, <=2 iter), then hot loop: broadcast LDS edge record
// + contiguous 128/256B global h gather (L2 hit) + 4*CH FMAs, unroll 4 (the
// R6-proven recipe). __launch_bounds__(256,8) pins VGPR <= 64 — crossing the
// occupancy step (65 VGPR would halve waves/SIMD; R11 measured 68 -> 21% occ).
// Lean body (live ~50 VGPR) fits without spills (R8's spill was the fat
// unroll-8 body). Quadrant runs give static accumulator targets.
template<int CH>
__global__ __launch_bounds__(256, 8) void gather_kernel(
    const _Float16* __restrict__ hsrc,   // [16384][CIN] fp16
    const float4* __restrict__ edge, const int4* __restrict__ cnt4,
    const float* __restrict__ deginv,
    _Float16* __restrict__ sp) {         // [16384][KP]
  const int CIN = 64 * CH, KP = 10 * CIN;
  __shared__ float4 esh[4][CAP];
  int wave = threadIdx.x >> 6, lane = threadIdx.x & 63;
  int xcd = blockIdx.x & 7;
  int j = blockIdx.x >> 3;
  int b = xcd * 4 + (j >> 7);
  int n = ((j & 127) << 2) + wave;          // row within batch
  int row = (b << 9) + n;
  int4 c4 = cnt4[row];
  int e1 = c4.x, e2 = e1 + c4.y, e3 = e2 + c4.z, e4 = e3 + c4.w;
  size_t ebase = (size_t)row * CAP;
  for (int i = lane; i < e4; i += 64)
    esh[wave][i] = edge[ebase + i];         // wave-private region, no barrier
  float di = deginv[row];
  const _Float16* hb = hsrc + (size_t)b * N_ * CIN + lane * CH;

  float acc[3][3][CH];
  #pragma unroll
  for (int kx = 0; kx < 3; ++kx)
    #pragma unroll
    for (int ky = 0; ky < 3; ++ky)
      #pragma unroll
      for (int c = 0; c < CH; ++c) acc[kx][ky][c] = 0.0f;

#define EDGE_BODY(E, KX, KY) {                                        \
    float4 er = esh[wave][E];                                         \
    int m = __float_as_int(er.x);                                     \
    float hv[CH];                                                     \
    if (CH == 1) {                                                    \
      hv[0] = (float)hb[(size_t)m * 64];                              \
    } else {                                                          \
      unsigned u = *(const unsigned*)&hb[(size_t)m * 128];            \
      f16x2 hp = __builtin_bit_cast(f16x2, u);                        \
      hv[0] = (float)hp[0]; hv[CH - 1] = (float)hp[1];                \
    }                                                                 \
    float fx = er.y, fy = er.z;                                       \
    float gx = 1.0f - fx, gy = 1.0f - fy;                             \
    float w00 = gx * gy, w01 = gx * fy, w10 = fx * gy, w11 = fx * fy; \
    _Pragma("unroll")                                                 \
    for (int c = 0; c < CH; ++c) {                                    \
      acc[KX][KY][c]         += w00 * hv[c];                          \
      acc[KX][KY + 1][c]     += w01 * hv[c];                          \
      acc[KX + 1][KY][c]     += w10 * hv[c];                          \
      acc[KX + 1][KY + 1][c] += w11 * hv[c];                          \
    } }

  #pragma unroll 4
  for (int e = 0; e < e1; ++e) EDGE_BODY(e, 0, 0)    // quad0: kx0=0, ky0=0
  #pragma unroll 4
  for (int e = e1; e < e2; ++e) EDGE_BODY(e, 1, 0)   // quad1: kx0=1, ky0=0
  #pragma unroll 4
  for (int e = e2; e < e3; ++e) EDGE_BODY(e, 0, 1)   // quad2: kx0=0, ky0=1
  #pragma unroll 4
  for (int e = e3; e < e4; ++e) EDGE_BODY(e, 1, 1)   // quad3: kx0=1, ky0=1
#undef EDGE_BODY

  // store: k = kx*3 + ky (reference reshape order); cols k*CIN + lane*CH
  _Float16* sr = sp + (size_t)row * KP + lane * CH;
  #pragma unroll
  for (int kx = 0; kx < 3; ++kx)
    #pragma unroll
    for (int ky = 0; ky < 3; ++ky) {
      int k = kx * 3 + ky;
      if (CH == 1) {
        sr[(size_t)k * CIN] = (_Float16)(acc[kx][ky][0] * di);
      } else {
        f16x2 p;
        p[0] = (_Float16)(acc[kx][ky][0] * di);
        p[1] = (_Float16)(acc[kx][ky][CH - 1] * di);
        *(f16x2*)&sr[(size_t)k * CIN] = p;
      }
    }
  // root column: h passthrough
  if (CH == 1) {
    sr[(size_t)9 * CIN] = hb[(size_t)n * 64];
  } else {
    *(unsigned*)&sr[(size_t)9 * CIN] = *(const unsigned*)&hb[(size_t)n * 128];
  }
}

// ---------------- dense GEMM: out[m,f] = relu( A[m,:]@Wt[f,:] + bias[f] ) ----------------
// A fp16 [16384][KP], Wt fp16 [64][KP]. M-tile 64 (grid 256), 256 thr = 4 waves,
// wave owns 16 rows x 64 cols, 16x16x32 f16 MFMA. Double-buffered LDS with
// issue-early/write-late staging (T14). Epilogue: fp16 h-out and/or fused
// max-pool (atomicMax on uint bits, relu >= 0).
#define GBK  64
#define GLDK 72
__global__ __launch_bounds__(256) void gemm_s_kernel(
    const _Float16* __restrict__ A, const _Float16* __restrict__ Wt,
    const float* __restrict__ bias, _Float16* __restrict__ hout,
    unsigned int* __restrict__ gmax, int KP) {
  __shared__ __attribute__((aligned(16))) _Float16 As[2][64 * GLDK];
  __shared__ __attribute__((aligned(16))) _Float16 Ws[2][64 * GLDK];
  int bm = blockIdx.x << 6;
  int tid = threadIdx.x, wave = tid >> 6, lane = tid & 63;
  int lr = lane & 15, quad = lane >> 4;
  int srow = tid >> 3, sck = (tid & 7) * 8;       // staging: rows srow, srow+32
  const size_t aoff = (size_t)(bm + srow) * KP + sck;
  const size_t woff = (size_t)srow * KP + sck;

  f32x4 acc[4] = {};
  // stage step 0 directly
  {
    *(float4*)&As[0][srow * GLDK + sck]        = *(const float4*)&A[aoff];
    *(float4*)&As[0][(srow + 32) * GLDK + sck] = *(const float4*)&A[aoff + (size_t)32 * KP];
    *(float4*)&Ws[0][srow * GLDK + sck]        = *(const float4*)&Wt[woff];
    *(float4*)&Ws[0][(srow + 32) * GLDK + sck] = *(const float4*)&Wt[woff + (size_t)32 * KP];
  }
  int S = KP / GBK, cur = 0;
  float4 pa0, pa1, pw0, pw1;
  for (int s = 0; s < S; ++s) {
    if (s + 1 < S) {                 // issue next tile's loads (no wait)
      int k0 = (s + 1) * GBK;
      pa0 = *(const float4*)&A[aoff + k0];
      pa1 = *(const float4*)&A[aoff + (size_t)32 * KP + k0];
      pw0 = *(const float4*)&Wt[woff + k0];
      pw1 = *(const float4*)&Wt[woff + (size_t)32 * KP + k0];
    }
    __syncthreads();                 // buf[cur] ready for all waves
    #pragma unroll
    for (int kk = 0; kk < GBK; kk += 32) {
      f16x8 af = *(const f16x8*)&As[cur][(16 * wave + lr) * GLDK + kk + quad * 8];
      #pragma unroll
      for (int j = 0; j < 4; ++j) {
        f16x8 bf = *(const f16x8*)&Ws[cur][(16 * j + lr) * GLDK + kk + quad * 8];
        acc[j] = __builtin_amdgcn_mfma_f32_16x16x32_f16(af, bf, acc[j], 0, 0, 0);
      }
    }
    if (s + 1 < S) {                 // write-late into the other buffer
      int nb = cur ^ 1;
      *(float4*)&As[nb][srow * GLDK + sck]        = pa0;
      *(float4*)&As[nb][(srow + 32) * GLDK + sck] = pa1;
      *(float4*)&Ws[nb][srow * GLDK + sck]        = pw0;
      *(float4*)&Ws[nb][(srow + 32) * GLDK + sck] = pw1;
    }
    cur ^= 1;
  }
  // epilogue: C layout col = lane&15, row = quad*4 + r (verified)
  int b = bm >> 9;
  #pragma unroll
  for (int j = 0; j < 4; ++j) {
    int f = 16 * j + lr;
    float bs = bias[f];
    float vmax = 0.0f;
    #pragma unroll
    for (int r = 0; r < 4; ++r) {
      int m = bm + (wave << 4) + (quad << 2) + r;
      float v = fmaxf(acc[j][r] + bs, 0.0f);
      if (hout) hout[(size_t)m * F_ + f] = (_Float16)v;
      vmax = fmaxf(vmax, v);
    }
    if (gmax) atomicMax(&gmax[(b << 6) + f], __float_as_uint(vmax));
  }
}

// ---------------- FC from pooled features ----------------
__global__ __launch_bounds__(64) void fc_kernel(
    const float* __restrict__ g, const float* __restrict__ fcw,
    const float* __restrict__ fcb, float* __restrict__ out) {
  int b = blockIdx.x;
  int f = threadIdx.x;
  __shared__ float gs[64];
  gs[f] = g[b * F_ + f];
  __syncthreads();
  if (f < 10) {
    float s = fcb[f];
    #pragma unroll
    for (int c = 0; c < 64; ++c) s += gs[c] * fcw[c * 10 + f];
    out[b * 10 + f] = s;
  }
}

extern "C" void kernel_launch(void* const* d_in, const int* in_sizes, int n_in,
                              void* d_out, int out_size, void* d_ws, size_t ws_size,
                              hipStream_t stream) {
  const float* x     = (const float*)d_in[0];
  const float* coord = (const float*)d_in[1];
  const float* adj   = (const float*)d_in[2];
  const float* w0    = (const float*)d_in[3];
  const float* root0 = (const float*)d_in[4];
  const float* b0    = (const float*)d_in[5];
  const float* w1    = (const float*)d_in[6];
  const float* root1 = (const float*)d_in[7];
  const float* b1    = (const float*)d_in[8];
  const float* w2    = (const float*)d_in[9];
  const float* root2 = (const float*)d_in[10];
  const float* b2    = (const float*)d_in[11];
  const float* fcw   = (const float*)d_in[12];
  const float* fcb   = (const float*)d_in[13];
  float* out = (float*)d_out;

  char* ws = (char*)d_ws;
  size_t off = 0;
  auto alloc = [&](size_t bytes) {
    void* p = ws + off;
    off = (off + bytes + 255) & ~(size_t)255;
    return p;
  };
  const int R = B_ * N_;  // 16384
  float4* edge    = (float4*)alloc((size_t)R * CAP * 16);
  int4*   cnt4    = (int4*)  alloc((size_t)R * 16);
  float*  deginv  = (float*) alloc((size_t)R * 4);
  _Float16* hx    = (_Float16*)alloc((size_t)R * 128 * 2);   // fp16 x
  _Float16* wt0   = (_Float16*)alloc((size_t)64 * 1280 * 2);
  _Float16* wt1   = (_Float16*)alloc((size_t)64 * 640 * 2);
  _Float16* wt2   = (_Float16*)alloc((size_t)64 * 640 * 2);
  _Float16* sp    = (_Float16*)alloc((size_t)R * 1280 * 2);  // s (max K)
  _Float16* hA    = (_Float16*)alloc((size_t)R * 64 * 2);
  _Float16* hB    = (_Float16*)alloc((size_t)R * 64 * 2);
  unsigned int* gmax = (unsigned int*)alloc((size_t)B_ * F_ * 4);

  preprocess_kernel<<<R, 512, 0, stream>>>(
      adj, coord, edge, cnt4, deginv, gmax,
      x, hx, w0, root0, w1, root1, w2, root2, wt0, wt1, wt2);

  // layer 0: CIN=128, K = 1280
  gather_kernel<2><<<R / 4, 256, 0, stream>>>(hx, edge, cnt4, deginv, sp);
  gemm_s_kernel<<<R / 64, 256, 0, stream>>>(sp, wt0, b0, hA, nullptr, 1280);

  // layer 1: CIN=64, K = 640
  gather_kernel<1><<<R / 4, 256, 0, stream>>>(hA, edge, cnt4, deginv, sp);
  gemm_s_kernel<<<R / 64, 256, 0, stream>>>(sp, wt1, b1, hB, nullptr, 640);

  // layer 2: CIN=64, K = 640 — fused max-pool
  gather_kernel<1><<<R / 4, 256, 0, stream>>>(hB, edge, cnt4, deginv, sp);
  gemm_s_kernel<<<R / 64, 256, 0, stream>>>(sp, wt2, b2, nullptr, gmax, 640);

  fc_kernel<<<B_, 64, 0, stream>>>((const float*)gmax, fcw, fcb, out);
}

// Round 14
// 228.661 us; speedup vs baseline: 1.9723x; 1.0287x over previous
//
#include <hip/hip_runtime.h>

// SplineCNN on MI355X — aggregate-before-GEMM, L2-direct gather (R6/R13 structure).
//
// Math order: s[n, k*CIN+c] = deginv * sum_{m in N(n)} basis_k(n,m) * h[m,c],
// root column appended -> one dense GEMM per layer:
//   out = relu( [s | h] @ [w; root] + bias ),  K = 10*CIN, N = 64.
// Evidence R6-R13: gather wall ~35-40us/layer; R13's occupancy fix (VGPR<=64,
// 8 waves/SIMD) gave only ~4us -> gather is ~half VALU-work, half stall.
// THIS ROUND: hoist the per-edge tap-weight computation into preprocess —
// edge record split into edge_m (int) + edge_w (float4 {w00,w01,w10,w11} f32,
// computed ONCE per edge instead of redundantly by all 64 lanes every visit).
// Gather EDGE_BODY: 2 broadcast LDS reads -> h load -> 2 cvt -> 8 FMA
// (per-edge VALU 18->12 for CH=2, and a shorter load->FMA dependency chain).
// h read L2-direct (batch-XCD swizzle, slice <=512KB); edge lists LDS-staged;
// launch_bounds(256,8) keeps VGPR<=64 (R13-proven, no spills at unroll 4).
// All tensors fp16 (fp32 accumulate in gather + MFMA); layer-2 GEMM epilogue
// fuses global max-pool via uint-bitcast atomicMax (relu >= 0).

#define B_   32
#define N_   512
#define F_   64
#define CAP  128          // max neighbors per node (mean ~31; P(>128) ~ 18 sigma)

typedef float f32x4 __attribute__((ext_vector_type(4)));
typedef _Float16 f16x8 __attribute__((ext_vector_type(8)));
typedef _Float16 f16x2 __attribute__((ext_vector_type(2)));

// ---------------- preprocess: quadrant-sorted edge lists + merged prep ----------------
// edge_m[row*CAP+i] = neighbor index m; edge_w[row*CAP+i] = {w00,w01,w10,w11}
// (bilinear tap weights, f32, precomputed). Sorted by quad = kx0 + 2*ky0.
// cnt4[row] = per-quadrant counts (clamped to CAP); deginv = 1/clip(deg,1).
// Blocks 0..2047 zero the pooled-max buffer. First blocks also run merged prep:
// x fp32->fp16 (4 elems/thread) + pack [w;root] -> Wt fp16.
__global__ __launch_bounds__(512) void preprocess_kernel(
    const float* __restrict__ adj, const float* __restrict__ coord,
    int* __restrict__ edge_m, float4* __restrict__ edge_w,
    int4* __restrict__ cnt4,
    float* __restrict__ deginv, unsigned int* __restrict__ gmax,
    const float* __restrict__ x, _Float16* __restrict__ hx,
    const float* __restrict__ w0, const float* __restrict__ root0,
    const float* __restrict__ w1, const float* __restrict__ root1,
    const float* __restrict__ w2, const float* __restrict__ root2,
    _Float16* __restrict__ wt0, _Float16* __restrict__ wt1,
    _Float16* __restrict__ wt2) {
  int row = blockIdx.x;          // b*N + n
  int b = row >> 9;
  int tid = threadIdx.x;         // == m
  int lane = tid & 63, wave = tid >> 6;
  if (row < B_ * F_ && tid == 0) gmax[row] = 0u;

  // ---- merged prep: idx space [0, R*32) convx; then packw for 3 layers ----
  {
    int idx = row * 512 + tid;
    const int CX = B_ * N_ * 32;
    const int S0 = 64 * 1280, S1 = 64 * 640;
    if (idx < CX) {
      float4 v = ((const float4*)x)[idx];
      f16x2 p0, p1;
      p0[0] = (_Float16)v.x; p0[1] = (_Float16)v.y;
      p1[0] = (_Float16)v.z; p1[1] = (_Float16)v.w;
      uint2 u;
      u.x = __builtin_bit_cast(unsigned, p0);
      u.y = __builtin_bit_cast(unsigned, p1);
      ((uint2*)hx)[idx] = u;
    } else if (idx < CX + S0 + 2 * S1) {
      int r = idx - CX;
      const float *w, *root; _Float16* wt; int KP, CIN;
      if (r < S0)           { w = w0; root = root0; wt = wt0; KP = 1280; CIN = 128; }
      else if (r < S0 + S1) { w = w1; root = root1; wt = wt1; KP = 640;  CIN = 64;  r -= S0; }
      else                  { w = w2; root = root2; wt = wt2; KP = 640;  CIN = 64;  r -= S0 + S1; }
      int f = r / KP, k = r - f * KP;
      int ks = k / CIN, c = k - ks * CIN;
      float v = (ks < 9) ? w[((size_t)ks * CIN + c) * F_ + f]
                         : root[(size_t)c * F_ + f];
      wt[(size_t)f * KP + k] = (_Float16)v;
    }
  }

  __shared__ int wc[8][4];
  float a = adj[(size_t)row * N_ + tid];
  bool flag = (a != 0.0f);
  float cxn = coord[(size_t)row * 2 + 0];
  float cyn = coord[(size_t)row * 2 + 1];
  float cxm = coord[(size_t)(b * N_ + tid) * 2 + 0];
  float cym = coord[(size_t)(b * N_ + tid) * 2 + 1];
  float vx = (cxm - cxn + 1.0f);        // = u*2 (K-1 = 2, u in [0,1])
  float vy = (cym - cyn + 1.0f);
  float i0x = fminf(fmaxf(floorf(vx), 0.0f), 1.0f);
  float i0y = fminf(fmaxf(floorf(vy), 0.0f), 1.0f);
  float fx = vx - i0x, fy = vy - i0y;
  int quad = (int)i0x + 2 * (int)i0y;   // 0..3
  unsigned long long bq0 = __ballot(flag && quad == 0);
  unsigned long long bq1 = __ballot(flag && quad == 1);
  unsigned long long bq2 = __ballot(flag && quad == 2);
  unsigned long long bq3 = __ballot(flag && quad == 3);
  if (lane == 0) {
    wc[wave][0] = __popcll(bq0); wc[wave][1] = __popcll(bq1);
    wc[wave][2] = __popcll(bq2); wc[wave][3] = __popcll(bq3);
  }
  __syncthreads();
  int qt0 = 0, qt1 = 0, qt2 = 0, qt3 = 0;
  #pragma unroll
  for (int w2 = 0; w2 < 8; ++w2) {
    qt0 += wc[w2][0]; qt1 += wc[w2][1]; qt2 += wc[w2][2]; qt3 += wc[w2][3];
  }
  if (flag) {
    int off = 0;
    if (quad > 0) off += qt0;
    if (quad > 1) off += qt1;
    if (quad > 2) off += qt2;
    #pragma unroll
    for (int w2 = 0; w2 < 8; ++w2)
      if (w2 < wave) off += wc[w2][quad];
    unsigned long long myb = (quad == 0) ? bq0 : (quad == 1) ? bq1
                           : (quad == 2) ? bq2 : bq3;
    off += __popcll(myb & ((1ULL << lane) - 1ULL));
    if (off < CAP) {
      float gx = 1.0f - fx, gy = 1.0f - fy;
      edge_m[(size_t)row * CAP + off] = tid;
      edge_w[(size_t)row * CAP + off] =
          make_float4(gx * gy, gx * fy, fx * gy, fx * fy);
    }
  }
  if (tid == 0) {
    int rem = CAP;
    int c0 = min(qt0, rem); rem -= c0;
    int c1 = min(qt1, rem); rem -= c1;
    int c2 = min(qt2, rem); rem -= c2;
    int c3 = min(qt3, rem);
    cnt4[row] = make_int4(c0, c1, c2, c3);
    int total = qt0 + qt1 + qt2 + qt3;
    deginv[row] = 1.0f / (float)(total > 0 ? total : 1);
  }
}

// ---------------- gather: s[row, k*CIN + c] = deginv * sum basis_k * h[m,c] ----------------
// 256 threads = 4 waves, ONE ROW PER WAVE; grid 4096, XCD-swizzled so batch b's
// blocks share an XCD (h slice <=512KB L2-resident). Wave stages its row's edge
// list (m + precomputed weights) to LDS, then hot loop: 2 broadcast LDS reads
// + contiguous 128/256B global h gather (L2 hit) + 2 cvt + 4*CH FMAs, unroll 4.
// __launch_bounds__(256,8) pins VGPR <= 64 (8 waves/SIMD; R13-proven fit).
// Quadrant runs give static accumulator targets. CH = CIN/64 channels/lane.
template<int CH>
__global__ __launch_bounds__(256, 8) void gather_kernel(
    const _Float16* __restrict__ hsrc,   // [16384][CIN] fp16
    const int* __restrict__ edge_m, const float4* __restrict__ edge_w,
    const int4* __restrict__ cnt4,
    const float* __restrict__ deginv,
    _Float16* __restrict__ sp) {         // [16384][KP]
  const int CIN = 64 * CH, KP = 10 * CIN;
  __shared__ float4 eshw[4][CAP];
  __shared__ int eshm[4][CAP];
  int wave = threadIdx.x >> 6, lane = threadIdx.x & 63;
  int xcd = blockIdx.x & 7;
  int j = blockIdx.x >> 3;
  int b = xcd * 4 + (j >> 7);
  int n = ((j & 127) << 2) + wave;          // row within batch
  int row = (b << 9) + n;
  int4 c4 = cnt4[row];
  int e1 = c4.x, e2 = e1 + c4.y, e3 = e2 + c4.z, e4 = e3 + c4.w;
  size_t ebase = (size_t)row * CAP;
  for (int i = lane; i < e4; i += 64) {     // wave-private region, no barrier
    eshw[wave][i] = edge_w[ebase + i];
    eshm[wave][i] = edge_m[ebase + i];
  }
  float di = deginv[row];
  const _Float16* hb = hsrc + (size_t)b * N_ * CIN + lane * CH;

  float acc[3][3][CH];
  #pragma unroll
  for (int kx = 0; kx < 3; ++kx)
    #pragma unroll
    for (int ky = 0; ky < 3; ++ky)
      #pragma unroll
      for (int c = 0; c < CH; ++c) acc[kx][ky][c] = 0.0f;

#define EDGE_BODY(E, KX, KY) {                                        \
    int m = eshm[wave][E];                                            \
    float4 wv = eshw[wave][E];                                        \
    float hv[CH];                                                     \
    if (CH == 1) {                                                    \
      hv[0] = (float)hb[(size_t)m * 64];                              \
    } else {                                                          \
      unsigned u = *(const unsigned*)&hb[(size_t)m * 128];            \
      f16x2 hp = __builtin_bit_cast(f16x2, u);                        \
      hv[0] = (float)hp[0]; hv[CH - 1] = (float)hp[1];                \
    }                                                                 \
    _Pragma("unroll")                                                 \
    for (int c = 0; c < CH; ++c) {                                    \
      acc[KX][KY][c]         += wv.x * hv[c];                         \
      acc[KX][KY + 1][c]     += wv.y * hv[c];                         \
      acc[KX + 1][KY][c]     += wv.z * hv[c];                         \
      acc[KX + 1][KY + 1][c] += wv.w * hv[c];                         \
    } }

  #pragma unroll 4
  for (int e = 0; e < e1; ++e) EDGE_BODY(e, 0, 0)    // quad0: kx0=0, ky0=0
  #pragma unroll 4
  for (int e = e1; e < e2; ++e) EDGE_BODY(e, 1, 0)   // quad1: kx0=1, ky0=0
  #pragma unroll 4
  for (int e = e2; e < e3; ++e) EDGE_BODY(e, 0, 1)   // quad2: kx0=0, ky0=1
  #pragma unroll 4
  for (int e = e3; e < e4; ++e) EDGE_BODY(e, 1, 1)   // quad3: kx0=1, ky0=1
#undef EDGE_BODY

  // store: k = kx*3 + ky (reference reshape order); cols k*CIN + lane*CH
  _Float16* sr = sp + (size_t)row * KP + lane * CH;
  #pragma unroll
  for (int kx = 0; kx < 3; ++kx)
    #pragma unroll
    for (int ky = 0; ky < 3; ++ky) {
      int k = kx * 3 + ky;
      if (CH == 1) {
        sr[(size_t)k * CIN] = (_Float16)(acc[kx][ky][0] * di);
      } else {
        f16x2 p;
        p[0] = (_Float16)(acc[kx][ky][0] * di);
        p[1] = (_Float16)(acc[kx][ky][CH - 1] * di);
        *(f16x2*)&sr[(size_t)k * CIN] = p;
      }
    }
  // root column: h passthrough
  if (CH == 1) {
    sr[(size_t)9 * CIN] = hb[(size_t)n * 64];
  } else {
    *(unsigned*)&sr[(size_t)9 * CIN] = *(const unsigned*)&hb[(size_t)n * 128];
  }
}

// ---------------- dense GEMM: out[m,f] = relu( A[m,:]@Wt[f,:] + bias[f] ) ----------------
// A fp16 [16384][KP], Wt fp16 [64][KP]. M-tile 64 (grid 256), 256 thr = 4 waves,
// wave owns 16 rows x 64 cols, 16x16x32 f16 MFMA. Double-buffered LDS with
// issue-early/write-late staging (T14). Epilogue: fp16 h-out and/or fused
// max-pool (atomicMax on uint bits, relu >= 0).
#define GBK  64
#define GLDK 72
__global__ __launch_bounds__(256) void gemm_s_kernel(
    const _Float16* __restrict__ A, const _Float16* __restrict__ Wt,
    const float* __restrict__ bias, _Float16* __restrict__ hout,
    unsigned int* __restrict__ gmax, int KP) {
  __shared__ __attribute__((aligned(16))) _Float16 As[2][64 * GLDK];
  __shared__ __attribute__((aligned(16))) _Float16 Ws[2][64 * GLDK];
  int bm = blockIdx.x << 6;
  int tid = threadIdx.x, wave = tid >> 6, lane = tid & 63;
  int lr = lane & 15, quad = lane >> 4;
  int srow = tid >> 3, sck = (tid & 7) * 8;       // staging: rows srow, srow+32
  const size_t aoff = (size_t)(bm + srow) * KP + sck;
  const size_t woff = (size_t)srow * KP + sck;

  f32x4 acc[4] = {};
  // stage step 0 directly
  {
    *(float4*)&As[0][srow * GLDK + sck]        = *(const float4*)&A[aoff];
    *(float4*)&As[0][(srow + 32) * GLDK + sck] = *(const float4*)&A[aoff + (size_t)32 * KP];
    *(float4*)&Ws[0][srow * GLDK + sck]        = *(const float4*)&Wt[woff];
    *(float4*)&Ws[0][(srow + 32) * GLDK + sck] = *(const float4*)&Wt[woff + (size_t)32 * KP];
  }
  int S = KP / GBK, cur = 0;
  float4 pa0, pa1, pw0, pw1;
  for (int s = 0; s < S; ++s) {
    if (s + 1 < S) {                 // issue next tile's loads (no wait)
      int k0 = (s + 1) * GBK;
      pa0 = *(const float4*)&A[aoff + k0];
      pa1 = *(const float4*)&A[aoff + (size_t)32 * KP + k0];
      pw0 = *(const float4*)&Wt[woff + k0];
      pw1 = *(const float4*)&Wt[woff + (size_t)32 * KP + k0];
    }
    __syncthreads();                 // buf[cur] ready for all waves
    #pragma unroll
    for (int kk = 0; kk < GBK; kk += 32) {
      f16x8 af = *(const f16x8*)&As[cur][(16 * wave + lr) * GLDK + kk + quad * 8];
      #pragma unroll
      for (int j = 0; j < 4; ++j) {
        f16x8 bf = *(const f16x8*)&Ws[cur][(16 * j + lr) * GLDK + kk + quad * 8];
        acc[j] = __builtin_amdgcn_mfma_f32_16x16x32_f16(af, bf, acc[j], 0, 0, 0);
      }
    }
    if (s + 1 < S) {                 // write-late into the other buffer
      int nb = cur ^ 1;
      *(float4*)&As[nb][srow * GLDK + sck]        = pa0;
      *(float4*)&As[nb][(srow + 32) * GLDK + sck] = pa1;
      *(float4*)&Ws[nb][srow * GLDK + sck]        = pw0;
      *(float4*)&Ws[nb][(srow + 32) * GLDK + sck] = pw1;
    }
    cur ^= 1;
  }
  // epilogue: C layout col = lane&15, row = quad*4 + r (verified)
  int b = bm >> 9;
  #pragma unroll
  for (int j = 0; j < 4; ++j) {
    int f = 16 * j + lr;
    float bs = bias[f];
    float vmax = 0.0f;
    #pragma unroll
    for (int r = 0; r < 4; ++r) {
      int m = bm + (wave << 4) + (quad << 2) + r;
      float v = fmaxf(acc[j][r] + bs, 0.0f);
      if (hout) hout[(size_t)m * F_ + f] = (_Float16)v;
      vmax = fmaxf(vmax, v);
    }
    if (gmax) atomicMax(&gmax[(b << 6) + f], __float_as_uint(vmax));
  }
}

// ---------------- FC from pooled features ----------------
__global__ __launch_bounds__(64) void fc_kernel(
    const float* __restrict__ g, const float* __restrict__ fcw,
    const float* __restrict__ fcb, float* __restrict__ out) {
  int b = blockIdx.x;
  int f = threadIdx.x;
  __shared__ float gs[64];
  gs[f] = g[b * F_ + f];
  __syncthreads();
  if (f < 10) {
    float s = fcb[f];
    #pragma unroll
    for (int c = 0; c < 64; ++c) s += gs[c] * fcw[c * 10 + f];
    out[b * 10 + f] = s;
  }
}

extern "C" void kernel_launch(void* const* d_in, const int* in_sizes, int n_in,
                              void* d_out, int out_size, void* d_ws, size_t ws_size,
                              hipStream_t stream) {
  const float* x     = (const float*)d_in[0];
  const float* coord = (const float*)d_in[1];
  const float* adj   = (const float*)d_in[2];
  const float* w0    = (const float*)d_in[3];
  const float* root0 = (const float*)d_in[4];
  const float* b0    = (const float*)d_in[5];
  const float* w1    = (const float*)d_in[6];
  const float* root1 = (const float*)d_in[7];
  const float* b1    = (const float*)d_in[8];
  const float* w2    = (const float*)d_in[9];
  const float* root2 = (const float*)d_in[10];
  const float* b2    = (const float*)d_in[11];
  const float* fcw   = (const float*)d_in[12];
  const float* fcb   = (const float*)d_in[13];
  float* out = (float*)d_out;

  char* ws = (char*)d_ws;
  size_t off = 0;
  auto alloc = [&](size_t bytes) {
    void* p = ws + off;
    off = (off + bytes + 255) & ~(size_t)255;
    return p;
  };
  const int R = B_ * N_;  // 16384
  int*    edge_m  = (int*)   alloc((size_t)R * CAP * 4);
  float4* edge_w  = (float4*)alloc((size_t)R * CAP * 16);
  int4*   cnt4    = (int4*)  alloc((size_t)R * 16);
  float*  deginv  = (float*) alloc((size_t)R * 4);
  _Float16* hx    = (_Float16*)alloc((size_t)R * 128 * 2);   // fp16 x
  _Float16* wt0   = (_Float16*)alloc((size_t)64 * 1280 * 2);
  _Float16* wt1   = (_Float16*)alloc((size_t)64 * 640 * 2);
  _Float16* wt2   = (_Float16*)alloc((size_t)64 * 640 * 2);
  _Float16* sp    = (_Float16*)alloc((size_t)R * 1280 * 2);  // s (max K)
  _Float16* hA    = (_Float16*)alloc((size_t)R * 64 * 2);
  _Float16* hB    = (_Float16*)alloc((size_t)R * 64 * 2);
  unsigned int* gmax = (unsigned int*)alloc((size_t)B_ * F_ * 4);

  preprocess_kernel<<<R, 512, 0, stream>>>(
      adj, coord, edge_m, edge_w, cnt4, deginv, gmax,
      x, hx, w0, root0, w1, root1, w2, root2, wt0, wt1, wt2);

  // layer 0: CIN=128, K = 1280
  gather_kernel<2><<<R / 4, 256, 0, stream>>>(hx, edge_m, edge_w, cnt4, deginv, sp);
  gemm_s_kernel<<<R / 64, 256, 0, stream>>>(sp, wt0, b0, hA, nullptr, 1280);

  // layer 1: CIN=64, K = 640
  gather_kernel<1><<<R / 4, 256, 0, stream>>>(hA, edge_m, edge_w, cnt4, deginv, sp);
  gemm_s_kernel<<<R / 64, 256, 0, stream>>>(sp, wt1, b1, hB, nullptr, 640);

  // layer 2: CIN=64, K = 640 — fused max-pool
  gather_kernel<1><<<R / 4, 256, 0, stream>>>(hB, edge_m, edge_w, cnt4, deginv, sp);
  gemm_s_kernel<<<R / 64, 256, 0, stream>>>(sp, wt2, b2, nullptr, gmax, 640);

  fc_kernel<<<B_, 64, 0, stream>>>((const float*)gmax, fcw, fcb, out);
}